// Round 25
// baseline (93.251 us; speedup 1.0000x reference)
//
#include <hip/hip_runtime.h>

typedef _Float16 f16;
typedef f16  f16x8 __attribute__((ext_vector_type(8)));
typedef float f32x4 __attribute__((ext_vector_type(4)));

#define NPTS 4096
#define HW   24576
#define WID  192
#define CH   128
#define NCX  24
#define NCY  16
#define NCELL 384
#define EPS  0.15f

// ---- workspace layout (bytes) ----  (total 8978432, proven-safe size)
#define OFF_NNIDX   (0u)           // int[49152]
#define OFF_CORR    (196608u)      // region reused for pts/offs
#define OFF_SAMPLED (393216u)      // float[2][4096][128] = 4 MB
#define OFF_F3T     (4587520u)     // float[8192*128]
#define OFF_WHL     (8781824u)     // f16[3][2][128][128]
#define OFF_PTS     (OFF_CORR)             // float4[2][4096] = 131072 B
#define OFF_OFFS    (OFF_CORR + 131072u)   // int[2][385]     = 3080 B

__device__ __forceinline__ int cell_of(float u, float v) {
  int cx = (int)(u * 0.125f); cx = min(max(cx, 0), NCX - 1);
  int cy = (int)(v * 0.125f); cy = min(max(cy, 0), NCY - 1);
  return cy * NCX + cx;
}

// Fused prep: blocks 0..95 weight hi/lo split; 96..607 feat3d transpose;
// 608..609 point binning (parallel prefix scan).
__global__ __launch_bounds__(512) void k_prep(const float* __restrict__ w1,
                                              const float* __restrict__ w2,
                                              const float* __restrict__ w3,
                                              const float* __restrict__ feat3d,
                                              const float* __restrict__ uv,
                                              f16* __restrict__ whl,
                                              float* __restrict__ f3t,
                                              float4* __restrict__ pts,
                                              int* __restrict__ offs) {
#pragma clang fp contract(off)
  __shared__ __align__(16) char smem[8448];
  int blk = blockIdx.x;
  int tid = threadIdx.x;
  if (blk < 96) {               // ---- weight split: 96*512 = 49152
    int i = blk * 512 + tid;
    int layer = i >> 14;
    int r = i & 16383;
    int o = r >> 7, k = r & 127;
    float v;
    if (layer == 0)      v = w1[o * 131 + 3 + k];
    else if (layer == 1) v = w2[o * 128 + k];
    else                 v = w3[o * 128 + k];
    f16 h = (f16)v;
    f16 l = (f16)(v - (float)h);
    whl[(layer * 2 + 0) * 16384 + r] = h;
    whl[(layer * 2 + 1) * 16384 + r] = l;
  } else if (blk < 608) {       // ---- transpose tile 32c x 64p
    float (*tile)[65] = (float (*)[65])smem;
    int t = blk - 96;           // 0..511
    int b = t >> 8;
    int r = t & 255;
    int cg = r >> 6, pg = r & 63;
    int c0 = cg * 32, p0 = pg * 64;
    {
      int p = tid & 63;
      int c = tid >> 6;         // 0..7, step 8
      #pragma unroll
      for (int cc = 0; cc < 32; cc += 8)
        tile[c + cc][p] = feat3d[(size_t)(b * CH + c0 + c + cc) * NPTS + p0 + p];
    }
    __syncthreads();
    {
      int c = tid & 31;
      int p = tid >> 5;         // 0..15, step 16
      #pragma unroll
      for (int pp = 0; pp < 64; pp += 16)
        f3t[(size_t)(b * NPTS + p0 + p + pp) * CH + c0 + c] = tile[c][p + pp];
    }
  } else {                      // ---- binning (2 blocks)
    int* cnt  = (int*)smem;                 // [NCELL]
    int* base = cnt + NCELL;                // [NCELL+1]
    int* sc   = base + NCELL + 1;           // [512]
    int b = blk - 608;
    const float* up = uv + b * 2 * NPTS;
    for (int i = tid; i < NCELL; i += 512) cnt[i] = 0;
    __syncthreads();
    for (int p = tid; p < NPTS; p += 512)
      atomicAdd(&cnt[cell_of(up[p], up[NPTS + p])], 1);
    __syncthreads();
    sc[tid] = (tid < NCELL) ? cnt[tid] : 0;
    __syncthreads();
    #pragma unroll
    for (int off = 1; off < 512; off <<= 1) {
      int val = (tid >= off) ? sc[tid - off] : 0;
      __syncthreads();
      sc[tid] += val;
      __syncthreads();
    }
    if (tid < NCELL) base[tid + 1] = sc[tid];
    if (tid == 0) base[0] = 0;
    __syncthreads();
    for (int i = tid; i <= NCELL; i += 512) offs[b * (NCELL + 1) + i] = base[i];
    for (int i = tid; i < NCELL; i += 512) cnt[i] = base[i];
    __syncthreads();
    for (int p = tid; p < NPTS; p += 512) {
      float u = up[p], v = up[NPTS + p];
      int pos = atomicAdd(&cnt[cell_of(u, v)], 1);
      float uu = u * u;   asm volatile("" : "+v"(uu));
      float vv = v * v;   asm volatile("" : "+v"(vv));
      float ss = uu + vv; asm volatile("" : "+v"(ss));
      float4 t; t.x = u; t.y = v; t.z = ss; t.w = __int_as_float(p);
      pts[b * NPTS + pos] = t;
    }
  }
}

// Blocks 0..95: NN query, 8 tiles per 512-thr block (one WAVE per 8x8 pixel
// tile; NO block barriers in this path -- wave-local shfl only). Bit-exact
// pinned ref d2; lexicographic (d2,idx) min == first-index strict-<.
// Blocks 96..351: binned-order sampling, 32 ranks per block, 4 ranks
// concurrent (tid>>7) x 8 iterations, unroll-4 -> ~16 gathers in flight.
__global__ __launch_bounds__(512) void k_nnq(const float4* __restrict__ pts,
                                             const int* __restrict__ offs,
                                             const float* __restrict__ feat2d,
                                             int* __restrict__ nn_idx,
                                             float* __restrict__ sampled) {
#pragma clang fp contract(off)
  int blk = blockIdx.x;
  int tid = threadIdx.x;
  if (blk >= 96) {              // ---- binned-order sampling
    int t = blk - 96;           // 0..255
    int b = t >> 7;
    int r0 = (t & 127) * 32;
    int c = tid & 127;
    int rsub = tid >> 7;        // 0..3
    const float* fp = feat2d + (size_t)(b * CH + c) * HW;
    #pragma unroll 4
    for (int rr = 0; rr < 8; ++rr) {
      int rank = r0 + rr * 4 + rsub;
      float4 pt = pts[b * NPTS + rank];
      float u = pt.x, v = pt.y;
      int p = __float_as_int(pt.w);
      float x0f = floorf(u), y0f = floorf(v);
      float wx = u - x0f, wy = v - y0f;
      int x0 = (int)x0f; x0 = min(max(x0, 0), WID - 1);
      int x1 = min(x0 + 1, WID - 1);
      int y0 = (int)y0f; y0 = min(max(y0, 0), 127);
      int y1 = min(y0 + 1, 127);
      float g00 = fp[y0 * WID + x0], g01 = fp[y0 * WID + x1];
      float g10 = fp[y1 * WID + x0], g11 = fp[y1 * WID + x1];
      float s = g00 * (1.f - wx) * (1.f - wy) + g01 * wx * (1.f - wy)
              + g10 * (1.f - wx) * wy + g11 * wx * wy;
      sampled[(size_t)(b * NPTS + p) * CH + c] = s;
    }
    return;
  }
  int tile = blk * 8 + (tid >> 6);   // 768 tiles
  int lane = tid & 63;
  int b = tile / NCELL;
  int t = tile - b * NCELL;
  int ty = t / NCX, tx = t - ty * NCX;
  int px = tx * 8 + (lane & 7);
  int py = ty * 8 + (lane >> 3);
  float xq = (float)px, yq = (float)py;
  float ssg = xq * xq + yq * yq;
  const float4* P = pts + b * NPTS;
  const int* O = offs + b * (NCELL + 1);

  float m = 3.4e38f;
  float bestr = 3.4e38f; int bir = 0x7fffffff;

  for (int R = 0; R < 24; ++R) {
    if (R > 0) {
      float mm = m;
      #pragma unroll
      for (int o = 32; o; o >>= 1) mm = fmaxf(mm, __shfl_xor(mm, o));
      float bound = 64.f * (float)((R - 1) * (R - 1));
      if (bound > mm + EPS) break;
    }
    int x0 = max(0, tx - R), x1 = min(NCX - 1, tx + R);
    int y0 = max(0, ty - R), y1 = min(NCY - 1, ty + R);
    for (int cy = y0; cy <= y1; ++cy) {
      for (int cx = x0; cx <= x1; ++cx) {
        int cd = max(abs(cx - tx), abs(cy - ty));
        if (cd != R) continue;
        int c = cy * NCX + cx;
        int s = O[c], e = O[c + 1];
        for (int i = s; i < e; ++i) {
          float4 pt = P[i];
          float dx = xq - pt.x, dy = yq - pt.y;
          float d2a = fmaf(dy, dy, dx * dx);
          m = fminf(m, d2a);
          if (d2a <= m + EPS) {
            float xu = xq * pt.x;                       asm volatile("" : "+v"(xu));
            float qp = __builtin_fmaf(yq, pt.y, xu);    asm volatile("" : "+v"(qp));
            float tq = 2.0f * qp;                       asm volatile("" : "+v"(tq));
            float t1 = ssg - tq;                        asm volatile("" : "+v"(t1));
            float d2 = t1 + pt.z;                       asm volatile("" : "+v"(d2));
            int pi = __float_as_int(pt.w);
            if (d2 < bestr || (d2 == bestr && pi < bir)) { bestr = d2; bir = pi; }
          }
        }
      }
    }
  }
  nn_idx[b * HW + py * WID + px] = bir;
}

// One conv layer via split-f16 MFMA: acc += Wh*xh + Wh*xl + Wl*xh, f32 accum.
template<bool LAYER1, bool LAST>
__device__ __forceinline__ void conv_layer(float* buf, const f16* wh, const f16* wl,
                                           const float* bias, const float* w1full,
                                           float* og, int wv, int l15, int l4) {
  f32x4 acc[2][4];
  #pragma unroll
  for (int r = 0; r < 2; ++r)
    #pragma unroll
    for (int c = 0; c < 4; ++c) acc[r][c] = (f32x4){0.f, 0.f, 0.f, 0.f};

  for (int k0 = 0; k0 < 128; k0 += 32) {
    f16x8 ah0 = *(const f16x8*)&wh[(wv * 32 + l15) * 128 + k0 + l4 * 8];
    f16x8 ah1 = *(const f16x8*)&wh[(wv * 32 + 16 + l15) * 128 + k0 + l4 * 8];
    f16x8 al0 = *(const f16x8*)&wl[(wv * 32 + l15) * 128 + k0 + l4 * 8];
    f16x8 al1 = *(const f16x8*)&wl[(wv * 32 + 16 + l15) * 128 + k0 + l4 * 8];
    #pragma unroll
    for (int c = 0; c < 4; ++c) {
      const float* bp = &buf[(c * 16 + l15) * 132 + k0 + l4 * 8];
      f32x4 v0 = *(const f32x4*)bp;
      f32x4 v1 = *(const f32x4*)(bp + 4);
      f16x8 bh, bl;
      #pragma unroll
      for (int i = 0; i < 4; ++i) {
        float x = v0[i]; f16 h = (f16)x; bh[i] = h; bl[i] = (f16)(x - (float)h);
        float x2 = v1[i]; f16 h2 = (f16)x2; bh[4 + i] = h2; bl[4 + i] = (f16)(x2 - (float)h2);
      }
      acc[0][c] = __builtin_amdgcn_mfma_f32_16x16x32_f16(ah0, bh, acc[0][c], 0, 0, 0);
      acc[0][c] = __builtin_amdgcn_mfma_f32_16x16x32_f16(ah0, bl, acc[0][c], 0, 0, 0);
      acc[0][c] = __builtin_amdgcn_mfma_f32_16x16x32_f16(al0, bh, acc[0][c], 0, 0, 0);
      acc[1][c] = __builtin_amdgcn_mfma_f32_16x16x32_f16(ah1, bh, acc[1][c], 0, 0, 0);
      acc[1][c] = __builtin_amdgcn_mfma_f32_16x16x32_f16(ah1, bl, acc[1][c], 0, 0, 0);
      acc[1][c] = __builtin_amdgcn_mfma_f32_16x16x32_f16(al1, bh, acc[1][c], 0, 0, 0);
    }
  }
  __syncthreads();
  #pragma unroll
  for (int r = 0; r < 2; ++r) {
    int ob = wv * 32 + r * 16 + l4 * 4;
    f32x4 bb = *(const f32x4*)&bias[ob];
    float w1c[4][3];
    if (LAYER1) {
      #pragma unroll
      for (int e = 0; e < 4; ++e) {
        w1c[e][0] = w1full[(ob + e) * 131 + 0];
        w1c[e][1] = w1full[(ob + e) * 131 + 1];
        w1c[e][2] = w1full[(ob + e) * 131 + 2];
      }
    }
    #pragma unroll
    for (int c = 0; c < 4; ++c) {
      int p = c * 16 + l15;
      float s0 = 0.f, s1 = 0.f, s2 = 0.f;
      if (LAYER1) { s0 = buf[p * 132 + 128]; s1 = buf[p * 132 + 129]; s2 = buf[p * 132 + 130]; }
      f32x4 yv;
      #pragma unroll
      for (int e = 0; e < 4; ++e) {
        float y = acc[r][c][e] + bb[e];
        if (LAYER1) y += w1c[e][0] * s0 + w1c[e][1] * s1 + w1c[e][2] * s2;
        y = (y >= 0.f) ? y : 0.1f * y;
        yv[e] = y;
        if (LAST) og[(size_t)(ob + e) * HW + p] = y;
      }
      if (!LAST) *(f32x4*)&buf[p * 132 + ob] = yv;
    }
  }
  __syncthreads();
}

// Fused corr + 3-layer conv. corr reads precomputed sampled rows (L2-hot)
// + coalesced f2[q]; accumulation order identical to the verified k_corr.
__global__ __launch_bounds__(256) void k_conv(const float* __restrict__ f3t,
                                              const int* __restrict__ nn_idx,
                                              const float* __restrict__ uv,
                                              const float* __restrict__ feat2d,
                                              const float* __restrict__ sampled,
                                              const f16* __restrict__ whl,
                                              const float* __restrict__ w1full,
                                              const float* __restrict__ b1,
                                              const float* __restrict__ b2,
                                              const float* __restrict__ b3,
                                              float* __restrict__ out) {
  __shared__ float buf[64 * 132];
  __shared__ int js[64];
  __shared__ float part[4][64];
  __shared__ float corrs[64];
  int blk = blockIdx.x;              // 768 = 2 * 384
  int b = blk / 384;
  int q0 = (blk - b * 384) * 64;
  int tid = threadIdx.x;
  int lane = tid & 63, wv = tid >> 6;
  int l15 = lane & 15, l4 = lane >> 4;

  if (tid < 64) js[tid] = nn_idx[b * HW + q0 + tid];
  __syncthreads();

  { // ---- corr phase ----
    int cg = tid >> 6, cpx = tid & 63;
    int q = q0 + cpx;
    int j = js[cpx];
    const float* sp = sampled + (size_t)(b * NPTS + j) * CH + cg * 32;
    const float* f2 = feat2d + (size_t)(b * CH + cg * 32) * HW + q;
    float acc = 0.f;
    #pragma unroll 8
    for (int i = 0; i < 32; ++i) acc += sp[i] * f2[(size_t)i * HW];
    part[cg][cpx] = acc;
    __syncthreads();
    if (cg == 0) {
      float s = (part[0][cpx] + part[1][cpx]) + (part[2][cpx] + part[3][cpx]);
      corrs[cpx] = s * 0.0078125f;
    }
    __syncthreads();
  }

  for (int i = tid; i < 64 * 33; i += 256) {
    int row = i / 33, c = i - row * 33;
    if (c < 32) {
      *(f32x4*)&buf[row * 132 + c * 4] =
          *(const f32x4*)&f3t[((size_t)(b * NPTS + js[row])) * CH + c * 4];
    } else {
      int q = q0 + row;
      int j = js[row];
      float u = uv[b * 2 * NPTS + j], v = uv[b * 2 * NPTS + NPTS + j];
      float xq = (float)(q % WID), yq = (float)(q / WID);
      f32x4 t = {u - xq, v - yq, corrs[row], 0.f};
      *(f32x4*)&buf[row * 132 + 128] = t;
    }
  }
  __syncthreads();

  float* og = out + (size_t)b * CH * HW + q0;
  conv_layer<true,  false>(buf, whl + 0 * 16384, whl + 1 * 16384, b1, w1full, og, wv, l15, l4);
  conv_layer<false, false>(buf, whl + 2 * 16384, whl + 3 * 16384, b2, nullptr, og, wv, l15, l4);
  conv_layer<false, true >(buf, whl + 4 * 16384, whl + 5 * 16384, b3, nullptr, og, wv, l15, l4);
}

extern "C" void kernel_launch(void* const* d_in, const int* in_sizes, int n_in,
                              void* d_out, int out_size, void* d_ws, size_t ws_size,
                              hipStream_t stream) {
  const float* uv     = (const float*)d_in[0];
  const float* feat2d = (const float*)d_in[1];
  const float* feat3d = (const float*)d_in[2];
  const float* w1 = (const float*)d_in[3];
  const float* b1 = (const float*)d_in[4];
  const float* w2 = (const float*)d_in[5];
  const float* b2 = (const float*)d_in[6];
  const float* w3 = (const float*)d_in[7];
  const float* b3 = (const float*)d_in[8];
  float* out = (float*)d_out;
  char* ws = (char*)d_ws;
  int*    nn_idx  = (int*)(ws + OFF_NNIDX);
  float*  sampled = (float*)(ws + OFF_SAMPLED);
  float*  f3t     = (float*)(ws + OFF_F3T);
  f16*    whl     = (f16*)(ws + OFF_WHL);
  float4* pts     = (float4*)(ws + OFF_PTS);
  int*    offs    = (int*)(ws + OFF_OFFS);

  k_prep<<<dim3(610), dim3(512), 0, stream>>>(w1, w2, w3, feat3d, uv, whl, f3t,
                                              pts, offs);
  k_nnq <<<dim3(352), dim3(512), 0, stream>>>(pts, offs, feat2d, nn_idx, sampled);
  k_conv<<<dim3(768), dim3(256), 0, stream>>>(f3t, nn_idx, uv, feat2d, sampled,
                                              whl, w1, b1, b2, b3, out);
}

// Round 26
// 92.274 us; speedup vs baseline: 1.0106x; 1.0106x over previous
//
#include <hip/hip_runtime.h>

typedef _Float16 f16;
typedef f16  f16x8 __attribute__((ext_vector_type(8)));
typedef float f32x4 __attribute__((ext_vector_type(4)));

#define NPTS 4096
#define HW   24576
#define WID  192
#define CH   128
#define NCX  24
#define NCY  16
#define NCELL 384
#define EPS  0.15f

// ---- workspace layout (bytes) ----  (total 8978432, proven-safe size)
#define OFF_NNIDX   (0u)           // int[49152]
#define OFF_CORR    (196608u)      // region reused for pts/offs
#define OFF_SAMPLED (393216u)      // float[2][4096][128] = 4 MB
#define OFF_F3T     (4587520u)     // float[8192*128]
#define OFF_WHL     (8781824u)     // f16[3][2][128][128]
#define OFF_PTS     (OFF_CORR)             // float4[2][4096] = 131072 B
#define OFF_OFFS    (OFF_CORR + 131072u)   // int[2][385]     = 3080 B

__device__ __forceinline__ int cell_of(float u, float v) {
  int cx = (int)(u * 0.125f); cx = min(max(cx, 0), NCX - 1);
  int cy = (int)(v * 0.125f); cy = min(max(cy, 0), NCY - 1);
  return cy * NCX + cx;
}

// Fused prep: blocks 0..95 weight hi/lo split; 96..607 feat3d transpose;
// 608..609 point binning (parallel prefix scan).
__global__ __launch_bounds__(512) void k_prep(const float* __restrict__ w1,
                                              const float* __restrict__ w2,
                                              const float* __restrict__ w3,
                                              const float* __restrict__ feat3d,
                                              const float* __restrict__ uv,
                                              f16* __restrict__ whl,
                                              float* __restrict__ f3t,
                                              float4* __restrict__ pts,
                                              int* __restrict__ offs) {
#pragma clang fp contract(off)
  __shared__ __align__(16) char smem[8448];
  int blk = blockIdx.x;
  int tid = threadIdx.x;
  if (blk < 96) {               // ---- weight split: 96*512 = 49152
    int i = blk * 512 + tid;
    int layer = i >> 14;
    int r = i & 16383;
    int o = r >> 7, k = r & 127;
    float v;
    if (layer == 0)      v = w1[o * 131 + 3 + k];
    else if (layer == 1) v = w2[o * 128 + k];
    else                 v = w3[o * 128 + k];
    f16 h = (f16)v;
    f16 l = (f16)(v - (float)h);
    whl[(layer * 2 + 0) * 16384 + r] = h;
    whl[(layer * 2 + 1) * 16384 + r] = l;
  } else if (blk < 608) {       // ---- transpose tile 32c x 64p
    float (*tile)[65] = (float (*)[65])smem;
    int t = blk - 96;           // 0..511
    int b = t >> 8;
    int r = t & 255;
    int cg = r >> 6, pg = r & 63;
    int c0 = cg * 32, p0 = pg * 64;
    {
      int p = tid & 63;
      int c = tid >> 6;         // 0..7, step 8
      #pragma unroll
      for (int cc = 0; cc < 32; cc += 8)
        tile[c + cc][p] = feat3d[(size_t)(b * CH + c0 + c + cc) * NPTS + p0 + p];
    }
    __syncthreads();
    {
      int c = tid & 31;
      int p = tid >> 5;         // 0..15, step 16
      #pragma unroll
      for (int pp = 0; pp < 64; pp += 16)
        f3t[(size_t)(b * NPTS + p0 + p + pp) * CH + c0 + c] = tile[c][p + pp];
    }
  } else {                      // ---- binning (2 blocks)
    int* cnt  = (int*)smem;                 // [NCELL]
    int* base = cnt + NCELL;                // [NCELL+1]
    int* sc   = base + NCELL + 1;           // [512]
    int b = blk - 608;
    const float* up = uv + b * 2 * NPTS;
    for (int i = tid; i < NCELL; i += 512) cnt[i] = 0;
    __syncthreads();
    for (int p = tid; p < NPTS; p += 512)
      atomicAdd(&cnt[cell_of(up[p], up[NPTS + p])], 1);
    __syncthreads();
    sc[tid] = (tid < NCELL) ? cnt[tid] : 0;
    __syncthreads();
    #pragma unroll
    for (int off = 1; off < 512; off <<= 1) {
      int val = (tid >= off) ? sc[tid - off] : 0;
      __syncthreads();
      sc[tid] += val;
      __syncthreads();
    }
    if (tid < NCELL) base[tid + 1] = sc[tid];
    if (tid == 0) base[0] = 0;
    __syncthreads();
    for (int i = tid; i <= NCELL; i += 512) offs[b * (NCELL + 1) + i] = base[i];
    for (int i = tid; i < NCELL; i += 512) cnt[i] = base[i];
    __syncthreads();
    for (int p = tid; p < NPTS; p += 512) {
      float u = up[p], v = up[NPTS + p];
      int pos = atomicAdd(&cnt[cell_of(u, v)], 1);
      float uu = u * u;   asm volatile("" : "+v"(uu));
      float vv = v * v;   asm volatile("" : "+v"(vv));
      float ss = uu + vv; asm volatile("" : "+v"(ss));
      float4 t; t.x = u; t.y = v; t.z = ss; t.w = __int_as_float(p);
      pts[b * NPTS + pos] = t;
    }
  }
}

// Blocks 0..95: NN query, 8 tiles per 512-thr block (wave-local shfl only).
// Bit-exact pinned ref d2; lexicographic (d2,idx) min == first-index strict-<.
// Blocks 96..351: binned-order sampling, 32 ranks/block; pts staged in LDS,
// 8-rank fully-unrolled batch -> 32 independent gathers in flight per wave.
// __launch_bounds__(512,1) lifts the VGPR ceiling so loads stay in flight.
__global__ __launch_bounds__(512, 1) void k_nnq(const float4* __restrict__ pts,
                                                const int* __restrict__ offs,
                                                const float* __restrict__ feat2d,
                                                int* __restrict__ nn_idx,
                                                float* __restrict__ sampled) {
#pragma clang fp contract(off)
  __shared__ float4 lpts[32];
  int blk = blockIdx.x;
  int tid = threadIdx.x;
  if (blk >= 96) {              // ---- binned-order sampling
    int t = blk - 96;           // 0..255
    int b = t >> 7;
    int r0 = (t & 127) * 32;
    int c = tid & 127;
    int rsub = tid >> 7;        // 0..3
    const float* fp = feat2d + (size_t)(b * CH + c) * HW;
    if (tid < 32) lpts[tid] = pts[b * NPTS + r0 + tid];
    __syncthreads();
    float g00[8], g01[8], g10[8], g11[8], wxa[8], wya[8];
    int pidx[8];
    #pragma unroll
    for (int k = 0; k < 8; ++k) {
      float4 pt = lpts[rsub + 4 * k];
      float u = pt.x, v = pt.y;
      pidx[k] = __float_as_int(pt.w);
      float x0f = floorf(u), y0f = floorf(v);
      wxa[k] = u - x0f; wya[k] = v - y0f;
      int x0 = (int)x0f; x0 = min(max(x0, 0), WID - 1);
      int x1 = min(x0 + 1, WID - 1);
      int y0 = (int)y0f; y0 = min(max(y0, 0), 127);
      int y1 = min(y0 + 1, 127);
      g00[k] = fp[y0 * WID + x0]; g01[k] = fp[y0 * WID + x1];
      g10[k] = fp[y1 * WID + x0]; g11[k] = fp[y1 * WID + x1];
    }
    #pragma unroll
    for (int k = 0; k < 8; ++k) {
      float wx = wxa[k], wy = wya[k];
      float s = g00[k] * (1.f - wx) * (1.f - wy) + g01[k] * wx * (1.f - wy)
              + g10[k] * (1.f - wx) * wy + g11[k] * wx * wy;
      sampled[(size_t)(b * NPTS + pidx[k]) * CH + c] = s;
    }
    return;
  }
  int tile = blk * 8 + (tid >> 6);   // 768 tiles
  int lane = tid & 63;
  int b = tile / NCELL;
  int t = tile - b * NCELL;
  int ty = t / NCX, tx = t - ty * NCX;
  int px = tx * 8 + (lane & 7);
  int py = ty * 8 + (lane >> 3);
  float xq = (float)px, yq = (float)py;
  float ssg = xq * xq + yq * yq;
  const float4* P = pts + b * NPTS;
  const int* O = offs + b * (NCELL + 1);

  float m = 3.4e38f;
  float bestr = 3.4e38f; int bir = 0x7fffffff;

  for (int R = 0; R < 24; ++R) {
    if (R > 0) {
      float mm = m;
      #pragma unroll
      for (int o = 32; o; o >>= 1) mm = fmaxf(mm, __shfl_xor(mm, o));
      float bound = 64.f * (float)((R - 1) * (R - 1));
      if (bound > mm + EPS) break;
    }
    int x0 = max(0, tx - R), x1 = min(NCX - 1, tx + R);
    int y0 = max(0, ty - R), y1 = min(NCY - 1, ty + R);
    for (int cy = y0; cy <= y1; ++cy) {
      for (int cx = x0; cx <= x1; ++cx) {
        int cd = max(abs(cx - tx), abs(cy - ty));
        if (cd != R) continue;
        int c = cy * NCX + cx;
        int s = O[c], e = O[c + 1];
        for (int i = s; i < e; ++i) {
          float4 pt = P[i];
          float dx = xq - pt.x, dy = yq - pt.y;
          float d2a = fmaf(dy, dy, dx * dx);
          m = fminf(m, d2a);
          if (d2a <= m + EPS) {
            float xu = xq * pt.x;                       asm volatile("" : "+v"(xu));
            float qp = __builtin_fmaf(yq, pt.y, xu);    asm volatile("" : "+v"(qp));
            float tq = 2.0f * qp;                       asm volatile("" : "+v"(tq));
            float t1 = ssg - tq;                        asm volatile("" : "+v"(t1));
            float d2 = t1 + pt.z;                       asm volatile("" : "+v"(d2));
            int pi = __float_as_int(pt.w);
            if (d2 < bestr || (d2 == bestr && pi < bir)) { bestr = d2; bir = pi; }
          }
        }
      }
    }
  }
  nn_idx[b * HW + py * WID + px] = bir;
}

// One conv layer via split-f16 MFMA: acc += Wh*xh + Wh*xl + Wl*xh, f32 accum.
template<bool LAYER1, bool LAST>
__device__ __forceinline__ void conv_layer(float* buf, const f16* wh, const f16* wl,
                                           const float* bias, const float* w1full,
                                           float* og, int wv, int l15, int l4) {
  f32x4 acc[2][4];
  #pragma unroll
  for (int r = 0; r < 2; ++r)
    #pragma unroll
    for (int c = 0; c < 4; ++c) acc[r][c] = (f32x4){0.f, 0.f, 0.f, 0.f};

  for (int k0 = 0; k0 < 128; k0 += 32) {
    f16x8 ah0 = *(const f16x8*)&wh[(wv * 32 + l15) * 128 + k0 + l4 * 8];
    f16x8 ah1 = *(const f16x8*)&wh[(wv * 32 + 16 + l15) * 128 + k0 + l4 * 8];
    f16x8 al0 = *(const f16x8*)&wl[(wv * 32 + l15) * 128 + k0 + l4 * 8];
    f16x8 al1 = *(const f16x8*)&wl[(wv * 32 + 16 + l15) * 128 + k0 + l4 * 8];
    #pragma unroll
    for (int c = 0; c < 4; ++c) {
      const float* bp = &buf[(c * 16 + l15) * 132 + k0 + l4 * 8];
      f32x4 v0 = *(const f32x4*)bp;
      f32x4 v1 = *(const f32x4*)(bp + 4);
      f16x8 bh, bl;
      #pragma unroll
      for (int i = 0; i < 4; ++i) {
        float x = v0[i]; f16 h = (f16)x; bh[i] = h; bl[i] = (f16)(x - (float)h);
        float x2 = v1[i]; f16 h2 = (f16)x2; bh[4 + i] = h2; bl[4 + i] = (f16)(x2 - (float)h2);
      }
      acc[0][c] = __builtin_amdgcn_mfma_f32_16x16x32_f16(ah0, bh, acc[0][c], 0, 0, 0);
      acc[0][c] = __builtin_amdgcn_mfma_f32_16x16x32_f16(ah0, bl, acc[0][c], 0, 0, 0);
      acc[0][c] = __builtin_amdgcn_mfma_f32_16x16x32_f16(al0, bh, acc[0][c], 0, 0, 0);
      acc[1][c] = __builtin_amdgcn_mfma_f32_16x16x32_f16(ah1, bh, acc[1][c], 0, 0, 0);
      acc[1][c] = __builtin_amdgcn_mfma_f32_16x16x32_f16(ah1, bl, acc[1][c], 0, 0, 0);
      acc[1][c] = __builtin_amdgcn_mfma_f32_16x16x32_f16(al1, bh, acc[1][c], 0, 0, 0);
    }
  }
  __syncthreads();
  #pragma unroll
  for (int r = 0; r < 2; ++r) {
    int ob = wv * 32 + r * 16 + l4 * 4;
    f32x4 bb = *(const f32x4*)&bias[ob];
    float w1c[4][3];
    if (LAYER1) {
      #pragma unroll
      for (int e = 0; e < 4; ++e) {
        w1c[e][0] = w1full[(ob + e) * 131 + 0];
        w1c[e][1] = w1full[(ob + e) * 131 + 1];
        w1c[e][2] = w1full[(ob + e) * 131 + 2];
      }
    }
    #pragma unroll
    for (int c = 0; c < 4; ++c) {
      int p = c * 16 + l15;
      float s0 = 0.f, s1 = 0.f, s2 = 0.f;
      if (LAYER1) { s0 = buf[p * 132 + 128]; s1 = buf[p * 132 + 129]; s2 = buf[p * 132 + 130]; }
      f32x4 yv;
      #pragma unroll
      for (int e = 0; e < 4; ++e) {
        float y = acc[r][c][e] + bb[e];
        if (LAYER1) y += w1c[e][0] * s0 + w1c[e][1] * s1 + w1c[e][2] * s2;
        y = (y >= 0.f) ? y : 0.1f * y;
        yv[e] = y;
        if (LAST) og[(size_t)(ob + e) * HW + p] = y;
      }
      if (!LAST) *(f32x4*)&buf[p * 132 + ob] = yv;
    }
  }
  __syncthreads();
}

// Fused corr + 3-layer conv. corr reads precomputed sampled rows (L2-hot)
// + coalesced f2[q]; accumulation order identical to the verified k_corr.
__global__ __launch_bounds__(256) void k_conv(const float* __restrict__ f3t,
                                              const int* __restrict__ nn_idx,
                                              const float* __restrict__ uv,
                                              const float* __restrict__ feat2d,
                                              const float* __restrict__ sampled,
                                              const f16* __restrict__ whl,
                                              const float* __restrict__ w1full,
                                              const float* __restrict__ b1,
                                              const float* __restrict__ b2,
                                              const float* __restrict__ b3,
                                              float* __restrict__ out) {
  __shared__ float buf[64 * 132];
  __shared__ int js[64];
  __shared__ float part[4][64];
  __shared__ float corrs[64];
  int blk = blockIdx.x;              // 768 = 2 * 384
  int b = blk / 384;
  int q0 = (blk - b * 384) * 64;
  int tid = threadIdx.x;
  int lane = tid & 63, wv = tid >> 6;
  int l15 = lane & 15, l4 = lane >> 4;

  if (tid < 64) js[tid] = nn_idx[b * HW + q0 + tid];
  __syncthreads();

  { // ---- corr phase ----
    int cg = tid >> 6, cpx = tid & 63;
    int q = q0 + cpx;
    int j = js[cpx];
    const float* sp = sampled + (size_t)(b * NPTS + j) * CH + cg * 32;
    const float* f2 = feat2d + (size_t)(b * CH + cg * 32) * HW + q;
    float acc = 0.f;
    #pragma unroll 8
    for (int i = 0; i < 32; ++i) acc += sp[i] * f2[(size_t)i * HW];
    part[cg][cpx] = acc;
    __syncthreads();
    if (cg == 0) {
      float s = (part[0][cpx] + part[1][cpx]) + (part[2][cpx] + part[3][cpx]);
      corrs[cpx] = s * 0.0078125f;
    }
    __syncthreads();
  }

  for (int i = tid; i < 64 * 33; i += 256) {
    int row = i / 33, c = i - row * 33;
    if (c < 32) {
      *(f32x4*)&buf[row * 132 + c * 4] =
          *(const f32x4*)&f3t[((size_t)(b * NPTS + js[row])) * CH + c * 4];
    } else {
      int q = q0 + row;
      int j = js[row];
      float u = uv[b * 2 * NPTS + j], v = uv[b * 2 * NPTS + NPTS + j];
      float xq = (float)(q % WID), yq = (float)(q / WID);
      f32x4 t = {u - xq, v - yq, corrs[row], 0.f};
      *(f32x4*)&buf[row * 132 + 128] = t;
    }
  }
  __syncthreads();

  float* og = out + (size_t)b * CH * HW + q0;
  conv_layer<true,  false>(buf, whl + 0 * 16384, whl + 1 * 16384, b1, w1full, og, wv, l15, l4);
  conv_layer<false, false>(buf, whl + 2 * 16384, whl + 3 * 16384, b2, nullptr, og, wv, l15, l4);
  conv_layer<false, true >(buf, whl + 4 * 16384, whl + 5 * 16384, b3, nullptr, og, wv, l15, l4);
}

extern "C" void kernel_launch(void* const* d_in, const int* in_sizes, int n_in,
                              void* d_out, int out_size, void* d_ws, size_t ws_size,
                              hipStream_t stream) {
  const float* uv     = (const float*)d_in[0];
  const float* feat2d = (const float*)d_in[1];
  const float* feat3d = (const float*)d_in[2];
  const float* w1 = (const float*)d_in[3];
  const float* b1 = (const float*)d_in[4];
  const float* w2 = (const float*)d_in[5];
  const float* b2 = (const float*)d_in[6];
  const float* w3 = (const float*)d_in[7];
  const float* b3 = (const float*)d_in[8];
  float* out = (float*)d_out;
  char* ws = (char*)d_ws;
  int*    nn_idx  = (int*)(ws + OFF_NNIDX);
  float*  sampled = (float*)(ws + OFF_SAMPLED);
  float*  f3t     = (float*)(ws + OFF_F3T);
  f16*    whl     = (f16*)(ws + OFF_WHL);
  float4* pts     = (float4*)(ws + OFF_PTS);
  int*    offs    = (int*)(ws + OFF_OFFS);

  k_prep<<<dim3(610), dim3(512), 0, stream>>>(w1, w2, w3, feat3d, uv, whl, f3t,
                                              pts, offs);
  k_nnq <<<dim3(352), dim3(512), 0, stream>>>(pts, offs, feat2d, nn_idx, sampled);
  k_conv<<<dim3(768), dim3(256), 0, stream>>>(f3t, nn_idx, uv, feat2d, sampled,
                                              whl, w1, b1, b2, b3, out);
}

// Round 27
// 82.851 us; speedup vs baseline: 1.1255x; 1.1137x over previous
//
#include <hip/hip_runtime.h>

typedef _Float16 f16;
typedef f16  f16x8 __attribute__((ext_vector_type(8)));
typedef float f32x4 __attribute__((ext_vector_type(4)));

#define NPTS 4096
#define HW   24576
#define WID  192
#define CH   128
#define NCX  24
#define NCY  16
#define NCELL 384
#define EPS  0.15f

// ---- workspace layout (bytes) ----  (total 8978432, proven-safe size)
#define OFF_NNIDX   (0u)           // int[49152]
#define OFF_CORR    (196608u)      // region reused for pts/offs
#define OFF_SAMPLED (393216u)      // float[2][4096][128] = 4 MB
#define OFF_F3T     (4587520u)     // float[8192*128]
#define OFF_WHL     (8781824u)     // f16[3][2][128][128]
#define OFF_PTS     (OFF_CORR)             // float4[2][4096] = 131072 B
#define OFF_OFFS    (OFF_CORR + 131072u)   // int[2][385]     = 3080 B

__device__ __forceinline__ int cell_of(float u, float v) {
  int cx = (int)(u * 0.125f); cx = min(max(cx, 0), NCX - 1);
  int cy = (int)(v * 0.125f); cy = min(max(cy, 0), NCY - 1);
  return cy * NCX + cx;
}

// Fused prep: blocks 0..95 weight hi/lo split; 96..607 feat3d transpose;
// 608..609 point binning (parallel prefix scan).
__global__ __launch_bounds__(512) void k_prep(const float* __restrict__ w1,
                                              const float* __restrict__ w2,
                                              const float* __restrict__ w3,
                                              const float* __restrict__ feat3d,
                                              const float* __restrict__ uv,
                                              f16* __restrict__ whl,
                                              float* __restrict__ f3t,
                                              float4* __restrict__ pts,
                                              int* __restrict__ offs) {
#pragma clang fp contract(off)
  __shared__ __align__(16) char smem[8448];
  int blk = blockIdx.x;
  int tid = threadIdx.x;
  if (blk < 96) {               // ---- weight split: 96*512 = 49152
    int i = blk * 512 + tid;
    int layer = i >> 14;
    int r = i & 16383;
    int o = r >> 7, k = r & 127;
    float v;
    if (layer == 0)      v = w1[o * 131 + 3 + k];
    else if (layer == 1) v = w2[o * 128 + k];
    else                 v = w3[o * 128 + k];
    f16 h = (f16)v;
    f16 l = (f16)(v - (float)h);
    whl[(layer * 2 + 0) * 16384 + r] = h;
    whl[(layer * 2 + 1) * 16384 + r] = l;
  } else if (blk < 608) {       // ---- transpose tile 32c x 64p
    float (*tile)[65] = (float (*)[65])smem;
    int t = blk - 96;           // 0..511
    int b = t >> 8;
    int r = t & 255;
    int cg = r >> 6, pg = r & 63;
    int c0 = cg * 32, p0 = pg * 64;
    {
      int p = tid & 63;
      int c = tid >> 6;         // 0..7, step 8
      #pragma unroll
      for (int cc = 0; cc < 32; cc += 8)
        tile[c + cc][p] = feat3d[(size_t)(b * CH + c0 + c + cc) * NPTS + p0 + p];
    }
    __syncthreads();
    {
      int c = tid & 31;
      int p = tid >> 5;         // 0..15, step 16
      #pragma unroll
      for (int pp = 0; pp < 64; pp += 16)
        f3t[(size_t)(b * NPTS + p0 + p + pp) * CH + c0 + c] = tile[c][p + pp];
    }
  } else {                      // ---- binning (2 blocks)
    int* cnt  = (int*)smem;                 // [NCELL]
    int* base = cnt + NCELL;                // [NCELL+1]
    int* sc   = base + NCELL + 1;           // [512]
    int b = blk - 608;
    const float* up = uv + b * 2 * NPTS;
    for (int i = tid; i < NCELL; i += 512) cnt[i] = 0;
    __syncthreads();
    for (int p = tid; p < NPTS; p += 512)
      atomicAdd(&cnt[cell_of(up[p], up[NPTS + p])], 1);
    __syncthreads();
    sc[tid] = (tid < NCELL) ? cnt[tid] : 0;
    __syncthreads();
    #pragma unroll
    for (int off = 1; off < 512; off <<= 1) {
      int val = (tid >= off) ? sc[tid - off] : 0;
      __syncthreads();
      sc[tid] += val;
      __syncthreads();
    }
    if (tid < NCELL) base[tid + 1] = sc[tid];
    if (tid == 0) base[0] = 0;
    __syncthreads();
    for (int i = tid; i <= NCELL; i += 512) offs[b * (NCELL + 1) + i] = base[i];
    for (int i = tid; i < NCELL; i += 512) cnt[i] = base[i];
    __syncthreads();
    for (int p = tid; p < NPTS; p += 512) {
      float u = up[p], v = up[NPTS + p];
      int pos = atomicAdd(&cnt[cell_of(u, v)], 1);
      float uu = u * u;   asm volatile("" : "+v"(uu));
      float vv = v * v;   asm volatile("" : "+v"(vv));
      float ss = uu + vv; asm volatile("" : "+v"(ss));
      float4 t; t.x = u; t.y = v; t.z = ss; t.w = __int_as_float(p);
      pts[b * NPTS + pos] = t;
    }
  }
}

// Candidate evaluation: bit-exact pinned reference d2 + (d2,idx) lex-min.
__device__ __forceinline__ void cand_eval(float xq, float yq, float ssg,
                                          float4 pt, float& bestr, int& bir) {
  float xu = xq * pt.x;                       asm volatile("" : "+v"(xu));
  float qp = __builtin_fmaf(yq, pt.y, xu);    asm volatile("" : "+v"(qp));
  float tq = 2.0f * qp;                       asm volatile("" : "+v"(tq));
  float t1 = ssg - tq;                        asm volatile("" : "+v"(t1));
  float d2 = t1 + pt.z;                       asm volatile("" : "+v"(d2));
  int pi = __float_as_int(pt.w);
  if (d2 < bestr || (d2 == bestr && pi < bir)) { bestr = d2; bir = pi; }
}

// Blocks 0..95: NN query, 8 tiles per 512-thr block (wave-local shfl only).
// Cell scan UNROLLED x4: 4 independent pts loads in flight; m-updates are
// batched (safe: m >= final_min always, and any ref-winner has
// d2a <= final_min + delta << EPS, so it passes the m+EPS test at any time).
// Blocks 96..351: binned-order sampling (R26 batched form).
__global__ __launch_bounds__(512, 1) void k_nnq(const float4* __restrict__ pts,
                                                const int* __restrict__ offs,
                                                const float* __restrict__ feat2d,
                                                int* __restrict__ nn_idx,
                                                float* __restrict__ sampled) {
#pragma clang fp contract(off)
  __shared__ float4 lpts[32];
  int blk = blockIdx.x;
  int tid = threadIdx.x;
  if (blk >= 96) {              // ---- binned-order sampling
    int t = blk - 96;           // 0..255
    int b = t >> 7;
    int r0 = (t & 127) * 32;
    int c = tid & 127;
    int rsub = tid >> 7;        // 0..3
    const float* fp = feat2d + (size_t)(b * CH + c) * HW;
    if (tid < 32) lpts[tid] = pts[b * NPTS + r0 + tid];
    __syncthreads();
    float g00[8], g01[8], g10[8], g11[8], wxa[8], wya[8];
    int pidx[8];
    #pragma unroll
    for (int k = 0; k < 8; ++k) {
      float4 pt = lpts[rsub + 4 * k];
      float u = pt.x, v = pt.y;
      pidx[k] = __float_as_int(pt.w);
      float x0f = floorf(u), y0f = floorf(v);
      wxa[k] = u - x0f; wya[k] = v - y0f;
      int x0 = (int)x0f; x0 = min(max(x0, 0), WID - 1);
      int x1 = min(x0 + 1, WID - 1);
      int y0 = (int)y0f; y0 = min(max(y0, 0), 127);
      int y1 = min(y0 + 1, 127);
      g00[k] = fp[y0 * WID + x0]; g01[k] = fp[y0 * WID + x1];
      g10[k] = fp[y1 * WID + x0]; g11[k] = fp[y1 * WID + x1];
    }
    #pragma unroll
    for (int k = 0; k < 8; ++k) {
      float wx = wxa[k], wy = wya[k];
      float s = g00[k] * (1.f - wx) * (1.f - wy) + g01[k] * wx * (1.f - wy)
              + g10[k] * (1.f - wx) * wy + g11[k] * wx * wy;
      sampled[(size_t)(b * NPTS + pidx[k]) * CH + c] = s;
    }
    return;
  }
  int tile = blk * 8 + (tid >> 6);   // 768 tiles
  int lane = tid & 63;
  int b = tile / NCELL;
  int t = tile - b * NCELL;
  int ty = t / NCX, tx = t - ty * NCX;
  int px = tx * 8 + (lane & 7);
  int py = ty * 8 + (lane >> 3);
  float xq = (float)px, yq = (float)py;
  float ssg = xq * xq + yq * yq;
  const float4* P = pts + b * NPTS;
  const int* O = offs + b * (NCELL + 1);

  float m = 3.4e38f;
  float bestr = 3.4e38f; int bir = 0x7fffffff;

  for (int R = 0; R < 24; ++R) {
    if (R > 0) {
      float mm = m;
      #pragma unroll
      for (int o = 32; o; o >>= 1) mm = fmaxf(mm, __shfl_xor(mm, o));
      float bound = 64.f * (float)((R - 1) * (R - 1));
      if (bound > mm + EPS) break;
    }
    int x0 = max(0, tx - R), x1 = min(NCX - 1, tx + R);
    int y0 = max(0, ty - R), y1 = min(NCY - 1, ty + R);
    for (int cy = y0; cy <= y1; ++cy) {
      for (int cx = x0; cx <= x1; ++cx) {
        int cd = max(abs(cx - tx), abs(cy - ty));
        if (cd != R) continue;
        int c = cy * NCX + cx;
        int s = O[c], e = O[c + 1];
        int i = s;
        for (; i + 4 <= e; i += 4) {
          float4 p0 = P[i], p1 = P[i + 1], p2 = P[i + 2], p3 = P[i + 3];
          float dx0 = xq - p0.x, dy0 = yq - p0.y;
          float dx1 = xq - p1.x, dy1 = yq - p1.y;
          float dx2 = xq - p2.x, dy2 = yq - p2.y;
          float dx3 = xq - p3.x, dy3 = yq - p3.y;
          float a0 = fmaf(dy0, dy0, dx0 * dx0);
          float a1 = fmaf(dy1, dy1, dx1 * dx1);
          float a2 = fmaf(dy2, dy2, dx2 * dx2);
          float a3 = fmaf(dy3, dy3, dx3 * dx3);
          m = fminf(fminf(m, fminf(a0, a1)), fminf(a2, a3));
          if ((a0 <= m + EPS) | (a1 <= m + EPS) |
              (a2 <= m + EPS) | (a3 <= m + EPS)) {
            if (a0 <= m + EPS) cand_eval(xq, yq, ssg, p0, bestr, bir);
            if (a1 <= m + EPS) cand_eval(xq, yq, ssg, p1, bestr, bir);
            if (a2 <= m + EPS) cand_eval(xq, yq, ssg, p2, bestr, bir);
            if (a3 <= m + EPS) cand_eval(xq, yq, ssg, p3, bestr, bir);
          }
        }
        for (; i < e; ++i) {
          float4 pt = P[i];
          float dx = xq - pt.x, dy = yq - pt.y;
          float d2a = fmaf(dy, dy, dx * dx);
          m = fminf(m, d2a);
          if (d2a <= m + EPS) cand_eval(xq, yq, ssg, pt, bestr, bir);
        }
      }
    }
  }
  nn_idx[b * HW + py * WID + px] = bir;
}

// One conv layer via split-f16 MFMA: acc += Wh*xh + Wh*xl + Wl*xh, f32 accum.
template<bool LAYER1, bool LAST>
__device__ __forceinline__ void conv_layer(float* buf, const f16* wh, const f16* wl,
                                           const float* bias, const float* w1full,
                                           float* og, int wv, int l15, int l4) {
  f32x4 acc[2][4];
  #pragma unroll
  for (int r = 0; r < 2; ++r)
    #pragma unroll
    for (int c = 0; c < 4; ++c) acc[r][c] = (f32x4){0.f, 0.f, 0.f, 0.f};

  for (int k0 = 0; k0 < 128; k0 += 32) {
    f16x8 ah0 = *(const f16x8*)&wh[(wv * 32 + l15) * 128 + k0 + l4 * 8];
    f16x8 ah1 = *(const f16x8*)&wh[(wv * 32 + 16 + l15) * 128 + k0 + l4 * 8];
    f16x8 al0 = *(const f16x8*)&wl[(wv * 32 + l15) * 128 + k0 + l4 * 8];
    f16x8 al1 = *(const f16x8*)&wl[(wv * 32 + 16 + l15) * 128 + k0 + l4 * 8];
    #pragma unroll
    for (int c = 0; c < 4; ++c) {
      const float* bp = &buf[(c * 16 + l15) * 132 + k0 + l4 * 8];
      f32x4 v0 = *(const f32x4*)bp;
      f32x4 v1 = *(const f32x4*)(bp + 4);
      f16x8 bh, bl;
      #pragma unroll
      for (int i = 0; i < 4; ++i) {
        float x = v0[i]; f16 h = (f16)x; bh[i] = h; bl[i] = (f16)(x - (float)h);
        float x2 = v1[i]; f16 h2 = (f16)x2; bh[4 + i] = h2; bl[4 + i] = (f16)(x2 - (float)h2);
      }
      acc[0][c] = __builtin_amdgcn_mfma_f32_16x16x32_f16(ah0, bh, acc[0][c], 0, 0, 0);
      acc[0][c] = __builtin_amdgcn_mfma_f32_16x16x32_f16(ah0, bl, acc[0][c], 0, 0, 0);
      acc[0][c] = __builtin_amdgcn_mfma_f32_16x16x32_f16(al0, bh, acc[0][c], 0, 0, 0);
      acc[1][c] = __builtin_amdgcn_mfma_f32_16x16x32_f16(ah1, bh, acc[1][c], 0, 0, 0);
      acc[1][c] = __builtin_amdgcn_mfma_f32_16x16x32_f16(ah1, bl, acc[1][c], 0, 0, 0);
      acc[1][c] = __builtin_amdgcn_mfma_f32_16x16x32_f16(al1, bh, acc[1][c], 0, 0, 0);
    }
  }
  __syncthreads();
  #pragma unroll
  for (int r = 0; r < 2; ++r) {
    int ob = wv * 32 + r * 16 + l4 * 4;
    f32x4 bb = *(const f32x4*)&bias[ob];
    float w1c[4][3];
    if (LAYER1) {
      #pragma unroll
      for (int e = 0; e < 4; ++e) {
        w1c[e][0] = w1full[(ob + e) * 131 + 0];
        w1c[e][1] = w1full[(ob + e) * 131 + 1];
        w1c[e][2] = w1full[(ob + e) * 131 + 2];
      }
    }
    #pragma unroll
    for (int c = 0; c < 4; ++c) {
      int p = c * 16 + l15;
      float s0 = 0.f, s1 = 0.f, s2 = 0.f;
      if (LAYER1) { s0 = buf[p * 132 + 128]; s1 = buf[p * 132 + 129]; s2 = buf[p * 132 + 130]; }
      f32x4 yv;
      #pragma unroll
      for (int e = 0; e < 4; ++e) {
        float y = acc[r][c][e] + bb[e];
        if (LAYER1) y += w1c[e][0] * s0 + w1c[e][1] * s1 + w1c[e][2] * s2;
        y = (y >= 0.f) ? y : 0.1f * y;
        yv[e] = y;
        if (LAST) og[(size_t)(ob + e) * HW + p] = y;
      }
      if (!LAST) *(f32x4*)&buf[p * 132 + ob] = yv;
    }
  }
  __syncthreads();
}

// Fused corr + 3-layer conv. corr reads precomputed sampled rows (L2-hot)
// + coalesced f2[q]; accumulation order identical to the verified k_corr.
__global__ __launch_bounds__(256) void k_conv(const float* __restrict__ f3t,
                                              const int* __restrict__ nn_idx,
                                              const float* __restrict__ uv,
                                              const float* __restrict__ feat2d,
                                              const float* __restrict__ sampled,
                                              const f16* __restrict__ whl,
                                              const float* __restrict__ w1full,
                                              const float* __restrict__ b1,
                                              const float* __restrict__ b2,
                                              const float* __restrict__ b3,
                                              float* __restrict__ out) {
  __shared__ float buf[64 * 132];
  __shared__ int js[64];
  __shared__ float part[4][64];
  __shared__ float corrs[64];
  int blk = blockIdx.x;              // 768 = 2 * 384
  int b = blk / 384;
  int q0 = (blk - b * 384) * 64;
  int tid = threadIdx.x;
  int lane = tid & 63, wv = tid >> 6;
  int l15 = lane & 15, l4 = lane >> 4;

  if (tid < 64) js[tid] = nn_idx[b * HW + q0 + tid];
  __syncthreads();

  { // ---- corr phase ----
    int cg = tid >> 6, cpx = tid & 63;
    int q = q0 + cpx;
    int j = js[cpx];
    const float* sp = sampled + (size_t)(b * NPTS + j) * CH + cg * 32;
    const float* f2 = feat2d + (size_t)(b * CH + cg * 32) * HW + q;
    float acc = 0.f;
    #pragma unroll 8
    for (int i = 0; i < 32; ++i) acc += sp[i] * f2[(size_t)i * HW];
    part[cg][cpx] = acc;
    __syncthreads();
    if (cg == 0) {
      float s = (part[0][cpx] + part[1][cpx]) + (part[2][cpx] + part[3][cpx]);
      corrs[cpx] = s * 0.0078125f;
    }
    __syncthreads();
  }

  for (int i = tid; i < 64 * 33; i += 256) {
    int row = i / 33, c = i - row * 33;
    if (c < 32) {
      *(f32x4*)&buf[row * 132 + c * 4] =
          *(const f32x4*)&f3t[((size_t)(b * NPTS + js[row])) * CH + c * 4];
    } else {
      int q = q0 + row;
      int j = js[row];
      float u = uv[b * 2 * NPTS + j], v = uv[b * 2 * NPTS + NPTS + j];
      float xq = (float)(q % WID), yq = (float)(q / WID);
      f32x4 t = {u - xq, v - yq, corrs[row], 0.f};
      *(f32x4*)&buf[row * 132 + 128] = t;
    }
  }
  __syncthreads();

  float* og = out + (size_t)b * CH * HW + q0;
  conv_layer<true,  false>(buf, whl + 0 * 16384, whl + 1 * 16384, b1, w1full, og, wv, l15, l4);
  conv_layer<false, false>(buf, whl + 2 * 16384, whl + 3 * 16384, b2, nullptr, og, wv, l15, l4);
  conv_layer<false, true >(buf, whl + 4 * 16384, whl + 5 * 16384, b3, nullptr, og, wv, l15, l4);
}

extern "C" void kernel_launch(void* const* d_in, const int* in_sizes, int n_in,
                              void* d_out, int out_size, void* d_ws, size_t ws_size,
                              hipStream_t stream) {
  const float* uv     = (const float*)d_in[0];
  const float* feat2d = (const float*)d_in[1];
  const float* feat3d = (const float*)d_in[2];
  const float* w1 = (const float*)d_in[3];
  const float* b1 = (const float*)d_in[4];
  const float* w2 = (const float*)d_in[5];
  const float* b2 = (const float*)d_in[6];
  const float* w3 = (const float*)d_in[7];
  const float* b3 = (const float*)d_in[8];
  float* out = (float*)d_out;
  char* ws = (char*)d_ws;
  int*    nn_idx  = (int*)(ws + OFF_NNIDX);
  float*  sampled = (float*)(ws + OFF_SAMPLED);
  float*  f3t     = (float*)(ws + OFF_F3T);
  f16*    whl     = (f16*)(ws + OFF_WHL);
  float4* pts     = (float4*)(ws + OFF_PTS);
  int*    offs    = (int*)(ws + OFF_OFFS);

  k_prep<<<dim3(610), dim3(512), 0, stream>>>(w1, w2, w3, feat3d, uv, whl, f3t,
                                              pts, offs);
  k_nnq <<<dim3(352), dim3(512), 0, stream>>>(pts, offs, feat2d, nn_idx, sampled);
  k_conv<<<dim3(768), dim3(256), 0, stream>>>(f3t, nn_idx, uv, feat2d, sampled,
                                              whl, w1, b1, b2, b3, out);
}

// Round 28
// 80.382 us; speedup vs baseline: 1.1601x; 1.0307x over previous
//
#include <hip/hip_runtime.h>

typedef _Float16 f16;
typedef f16  f16x8 __attribute__((ext_vector_type(8)));
typedef float f32x4 __attribute__((ext_vector_type(4)));

#define NPTS 4096
#define HW   24576
#define WID  192
#define CH   128
#define NCX  24
#define NCY  16
#define NCELL 384
#define EPS  0.15f

// ---- workspace layout (bytes) ----  (total 8978432, proven-safe size)
#define OFF_NNIDX   (0u)           // int[49152]
#define OFF_CORR    (196608u)      // region reused for pts/offs
#define OFF_SAMPLED (393216u)      // float[2][4096][128] = 4 MB
#define OFF_F3T     (4587520u)     // float[8192*128]
#define OFF_WHL     (8781824u)     // f16[3][2][128][128]
#define OFF_PTS     (OFF_CORR)             // float4[2][4096] = 131072 B
#define OFF_OFFS    (OFF_CORR + 131072u)   // int[2][385]     = 3080 B

__device__ __forceinline__ int cell_of(float u, float v) {
  int cx = (int)(u * 0.125f); cx = min(max(cx, 0), NCX - 1);
  int cy = (int)(v * 0.125f); cy = min(max(cy, 0), NCY - 1);
  return cy * NCX + cx;
}

// Binning only (2 blocks): count -> Hillis-Steele scan -> scatter
// float4{u, v, ssu_pinned, idx}.  ssu = RN(RN(u*u)+RN(v*v)) pinned.
__global__ __launch_bounds__(512) void k_bin(const float* __restrict__ uv,
                                             float4* __restrict__ pts,
                                             int* __restrict__ offs) {
#pragma clang fp contract(off)
  __shared__ int cnt[NCELL];
  __shared__ int base[NCELL + 1];
  __shared__ int sc[512];
  int b = blockIdx.x;
  int tid = threadIdx.x;
  const float* up = uv + b * 2 * NPTS;
  for (int i = tid; i < NCELL; i += 512) cnt[i] = 0;
  __syncthreads();
  for (int p = tid; p < NPTS; p += 512)
    atomicAdd(&cnt[cell_of(up[p], up[NPTS + p])], 1);
  __syncthreads();
  sc[tid] = (tid < NCELL) ? cnt[tid] : 0;
  __syncthreads();
  #pragma unroll
  for (int off = 1; off < 512; off <<= 1) {
    int val = (tid >= off) ? sc[tid - off] : 0;
    __syncthreads();
    sc[tid] += val;
    __syncthreads();
  }
  if (tid < NCELL) base[tid + 1] = sc[tid];
  if (tid == 0) base[0] = 0;
  __syncthreads();
  for (int i = tid; i <= NCELL; i += 512) offs[b * (NCELL + 1) + i] = base[i];
  for (int i = tid; i < NCELL; i += 512) cnt[i] = base[i];
  __syncthreads();
  for (int p = tid; p < NPTS; p += 512) {
    float u = up[p], v = up[NPTS + p];
    int pos = atomicAdd(&cnt[cell_of(u, v)], 1);
    float uu = u * u;   asm volatile("" : "+v"(uu));
    float vv = v * v;   asm volatile("" : "+v"(vv));
    float ss = uu + vv; asm volatile("" : "+v"(ss));
    float4 t; t.x = u; t.y = v; t.z = ss; t.w = __int_as_float(p);
    pts[b * NPTS + pos] = t;
  }
}

// Candidate evaluation: bit-exact pinned reference d2 + (d2,idx) lex-min.
__device__ __forceinline__ void cand_eval(float xq, float yq, float ssg,
                                          float4 pt, float& bestr, int& bir) {
  float xu = xq * pt.x;                       asm volatile("" : "+v"(xu));
  float qp = __builtin_fmaf(yq, pt.y, xu);    asm volatile("" : "+v"(qp));
  float tq = 2.0f * qp;                       asm volatile("" : "+v"(tq));
  float t1 = ssg - tq;                        asm volatile("" : "+v"(t1));
  float d2 = t1 + pt.z;                       asm volatile("" : "+v"(d2));
  int pi = __float_as_int(pt.w);
  if (d2 < bestr || (d2 == bestr && pi < bir)) { bestr = d2; bir = pi; }
}

// Fused main: [0..95] NN query (8 tiles/block, wave-local shfl, bit-exact
// pinned d2, scan unrolled x4); [96..351] binned-order sampling (batched
// gathers); [352..863] feat3d transpose; [864..959] weight hi/lo split.
// The copy work (transpose/weights) fills the latency shadow of NN/sampling.
__global__ __launch_bounds__(512, 1) void k_main(const float4* __restrict__ pts,
                                                 const int* __restrict__ offs,
                                                 const float* __restrict__ feat2d,
                                                 const float* __restrict__ feat3d,
                                                 const float* __restrict__ w1,
                                                 const float* __restrict__ w2,
                                                 const float* __restrict__ w3,
                                                 int* __restrict__ nn_idx,
                                                 float* __restrict__ sampled,
                                                 float* __restrict__ f3t,
                                                 f16* __restrict__ whl) {
#pragma clang fp contract(off)
  __shared__ __align__(16) char smem[8448];
  int blk = blockIdx.x;
  int tid = threadIdx.x;
  if (blk >= 864) {             // ---- weight split: 96*512 = 49152
    int i = (blk - 864) * 512 + tid;
    int layer = i >> 14;
    int r = i & 16383;
    int o = r >> 7, k = r & 127;
    float v;
    if (layer == 0)      v = w1[o * 131 + 3 + k];
    else if (layer == 1) v = w2[o * 128 + k];
    else                 v = w3[o * 128 + k];
    f16 h = (f16)v;
    f16 l = (f16)(v - (float)h);
    whl[(layer * 2 + 0) * 16384 + r] = h;
    whl[(layer * 2 + 1) * 16384 + r] = l;
    return;
  }
  if (blk >= 352) {             // ---- transpose tile 32c x 64p (512 blocks)
    float (*tile)[65] = (float (*)[65])smem;
    int t = blk - 352;          // 0..511
    int b = t >> 8;
    int r = t & 255;
    int cg = r >> 6, pg = r & 63;
    int c0 = cg * 32, p0 = pg * 64;
    {
      int p = tid & 63;
      int c = tid >> 6;         // 0..7, step 8
      #pragma unroll
      for (int cc = 0; cc < 32; cc += 8)
        tile[c + cc][p] = feat3d[(size_t)(b * CH + c0 + c + cc) * NPTS + p0 + p];
    }
    __syncthreads();
    {
      int c = tid & 31;
      int p = tid >> 5;         // 0..15, step 16
      #pragma unroll
      for (int pp = 0; pp < 64; pp += 16)
        f3t[(size_t)(b * NPTS + p0 + p + pp) * CH + c0 + c] = tile[c][p + pp];
    }
    return;
  }
  if (blk >= 96) {              // ---- binned-order sampling (256 blocks)
    float4* lpts = (float4*)smem;           // [32]
    int t = blk - 96;           // 0..255
    int b = t >> 7;
    int r0 = (t & 127) * 32;
    int c = tid & 127;
    int rsub = tid >> 7;        // 0..3
    const float* fp = feat2d + (size_t)(b * CH + c) * HW;
    if (tid < 32) lpts[tid] = pts[b * NPTS + r0 + tid];
    __syncthreads();
    float g00[8], g01[8], g10[8], g11[8], wxa[8], wya[8];
    int pidx[8];
    #pragma unroll
    for (int k = 0; k < 8; ++k) {
      float4 pt = lpts[rsub + 4 * k];
      float u = pt.x, v = pt.y;
      pidx[k] = __float_as_int(pt.w);
      float x0f = floorf(u), y0f = floorf(v);
      wxa[k] = u - x0f; wya[k] = v - y0f;
      int x0 = (int)x0f; x0 = min(max(x0, 0), WID - 1);
      int x1 = min(x0 + 1, WID - 1);
      int y0 = (int)y0f; y0 = min(max(y0, 0), 127);
      int y1 = min(y0 + 1, 127);
      g00[k] = fp[y0 * WID + x0]; g01[k] = fp[y0 * WID + x1];
      g10[k] = fp[y1 * WID + x0]; g11[k] = fp[y1 * WID + x1];
    }
    #pragma unroll
    for (int k = 0; k < 8; ++k) {
      float wx = wxa[k], wy = wya[k];
      float s = g00[k] * (1.f - wx) * (1.f - wy) + g01[k] * wx * (1.f - wy)
              + g10[k] * (1.f - wx) * wy + g11[k] * wx * wy;
      sampled[(size_t)(b * NPTS + pidx[k]) * CH + c] = s;
    }
    return;
  }
  // ---- NN query (96 blocks, 8 tiles each)
  int tile = blk * 8 + (tid >> 6);   // 768 tiles
  int lane = tid & 63;
  int b = tile / NCELL;
  int t = tile - b * NCELL;
  int ty = t / NCX, tx = t - ty * NCX;
  int px = tx * 8 + (lane & 7);
  int py = ty * 8 + (lane >> 3);
  float xq = (float)px, yq = (float)py;
  float ssg = xq * xq + yq * yq;
  const float4* P = pts + b * NPTS;
  const int* O = offs + b * (NCELL + 1);

  float m = 3.4e38f;
  float bestr = 3.4e38f; int bir = 0x7fffffff;

  for (int R = 0; R < 24; ++R) {
    if (R > 0) {
      float mm = m;
      #pragma unroll
      for (int o = 32; o; o >>= 1) mm = fmaxf(mm, __shfl_xor(mm, o));
      float bound = 64.f * (float)((R - 1) * (R - 1));
      if (bound > mm + EPS) break;
    }
    int x0 = max(0, tx - R), x1 = min(NCX - 1, tx + R);
    int y0 = max(0, ty - R), y1 = min(NCY - 1, ty + R);
    for (int cy = y0; cy <= y1; ++cy) {
      for (int cx = x0; cx <= x1; ++cx) {
        int cd = max(abs(cx - tx), abs(cy - ty));
        if (cd != R) continue;
        int c = cy * NCX + cx;
        int s = O[c], e = O[c + 1];
        int i = s;
        for (; i + 4 <= e; i += 4) {
          float4 p0 = P[i], p1 = P[i + 1], p2 = P[i + 2], p3 = P[i + 3];
          float dx0 = xq - p0.x, dy0 = yq - p0.y;
          float dx1 = xq - p1.x, dy1 = yq - p1.y;
          float dx2 = xq - p2.x, dy2 = yq - p2.y;
          float dx3 = xq - p3.x, dy3 = yq - p3.y;
          float a0 = fmaf(dy0, dy0, dx0 * dx0);
          float a1 = fmaf(dy1, dy1, dx1 * dx1);
          float a2 = fmaf(dy2, dy2, dx2 * dx2);
          float a3 = fmaf(dy3, dy3, dx3 * dx3);
          m = fminf(fminf(m, fminf(a0, a1)), fminf(a2, a3));
          if ((a0 <= m + EPS) | (a1 <= m + EPS) |
              (a2 <= m + EPS) | (a3 <= m + EPS)) {
            if (a0 <= m + EPS) cand_eval(xq, yq, ssg, p0, bestr, bir);
            if (a1 <= m + EPS) cand_eval(xq, yq, ssg, p1, bestr, bir);
            if (a2 <= m + EPS) cand_eval(xq, yq, ssg, p2, bestr, bir);
            if (a3 <= m + EPS) cand_eval(xq, yq, ssg, p3, bestr, bir);
          }
        }
        for (; i < e; ++i) {
          float4 pt = P[i];
          float dx = xq - pt.x, dy = yq - pt.y;
          float d2a = fmaf(dy, dy, dx * dx);
          m = fminf(m, d2a);
          if (d2a <= m + EPS) cand_eval(xq, yq, ssg, pt, bestr, bir);
        }
      }
    }
  }
  nn_idx[b * HW + py * WID + px] = bir;
}

// One conv layer via split-f16 MFMA: acc += Wh*xh + Wh*xl + Wl*xh, f32 accum.
template<bool LAYER1, bool LAST>
__device__ __forceinline__ void conv_layer(float* buf, const f16* wh, const f16* wl,
                                           const float* bias, const float* w1full,
                                           float* og, int wv, int l15, int l4) {
  f32x4 acc[2][4];
  #pragma unroll
  for (int r = 0; r < 2; ++r)
    #pragma unroll
    for (int c = 0; c < 4; ++c) acc[r][c] = (f32x4){0.f, 0.f, 0.f, 0.f};

  for (int k0 = 0; k0 < 128; k0 += 32) {
    f16x8 ah0 = *(const f16x8*)&wh[(wv * 32 + l15) * 128 + k0 + l4 * 8];
    f16x8 ah1 = *(const f16x8*)&wh[(wv * 32 + 16 + l15) * 128 + k0 + l4 * 8];
    f16x8 al0 = *(const f16x8*)&wl[(wv * 32 + l15) * 128 + k0 + l4 * 8];
    f16x8 al1 = *(const f16x8*)&wl[(wv * 32 + 16 + l15) * 128 + k0 + l4 * 8];
    #pragma unroll
    for (int c = 0; c < 4; ++c) {
      const float* bp = &buf[(c * 16 + l15) * 132 + k0 + l4 * 8];
      f32x4 v0 = *(const f32x4*)bp;
      f32x4 v1 = *(const f32x4*)(bp + 4);
      f16x8 bh, bl;
      #pragma unroll
      for (int i = 0; i < 4; ++i) {
        float x = v0[i]; f16 h = (f16)x; bh[i] = h; bl[i] = (f16)(x - (float)h);
        float x2 = v1[i]; f16 h2 = (f16)x2; bh[4 + i] = h2; bl[4 + i] = (f16)(x2 - (float)h2);
      }
      acc[0][c] = __builtin_amdgcn_mfma_f32_16x16x32_f16(ah0, bh, acc[0][c], 0, 0, 0);
      acc[0][c] = __builtin_amdgcn_mfma_f32_16x16x32_f16(ah0, bl, acc[0][c], 0, 0, 0);
      acc[0][c] = __builtin_amdgcn_mfma_f32_16x16x32_f16(al0, bh, acc[0][c], 0, 0, 0);
      acc[1][c] = __builtin_amdgcn_mfma_f32_16x16x32_f16(ah1, bh, acc[1][c], 0, 0, 0);
      acc[1][c] = __builtin_amdgcn_mfma_f32_16x16x32_f16(ah1, bl, acc[1][c], 0, 0, 0);
      acc[1][c] = __builtin_amdgcn_mfma_f32_16x16x32_f16(al1, bh, acc[1][c], 0, 0, 0);
    }
  }
  __syncthreads();
  #pragma unroll
  for (int r = 0; r < 2; ++r) {
    int ob = wv * 32 + r * 16 + l4 * 4;
    f32x4 bb = *(const f32x4*)&bias[ob];
    float w1c[4][3];
    if (LAYER1) {
      #pragma unroll
      for (int e = 0; e < 4; ++e) {
        w1c[e][0] = w1full[(ob + e) * 131 + 0];
        w1c[e][1] = w1full[(ob + e) * 131 + 1];
        w1c[e][2] = w1full[(ob + e) * 131 + 2];
      }
    }
    #pragma unroll
    for (int c = 0; c < 4; ++c) {
      int p = c * 16 + l15;
      float s0 = 0.f, s1 = 0.f, s2 = 0.f;
      if (LAYER1) { s0 = buf[p * 132 + 128]; s1 = buf[p * 132 + 129]; s2 = buf[p * 132 + 130]; }
      f32x4 yv;
      #pragma unroll
      for (int e = 0; e < 4; ++e) {
        float y = acc[r][c][e] + bb[e];
        if (LAYER1) y += w1c[e][0] * s0 + w1c[e][1] * s1 + w1c[e][2] * s2;
        y = (y >= 0.f) ? y : 0.1f * y;
        yv[e] = y;
        if (LAST) og[(size_t)(ob + e) * HW + p] = y;
      }
      if (!LAST) *(f32x4*)&buf[p * 132 + ob] = yv;
    }
  }
  __syncthreads();
}

// Fused corr + 3-layer conv. corr reads precomputed sampled rows (L2-hot)
// + coalesced f2[q]; accumulation order identical to the verified k_corr.
__global__ __launch_bounds__(256) void k_conv(const float* __restrict__ f3t,
                                              const int* __restrict__ nn_idx,
                                              const float* __restrict__ uv,
                                              const float* __restrict__ feat2d,
                                              const float* __restrict__ sampled,
                                              const f16* __restrict__ whl,
                                              const float* __restrict__ w1full,
                                              const float* __restrict__ b1,
                                              const float* __restrict__ b2,
                                              const float* __restrict__ b3,
                                              float* __restrict__ out) {
  __shared__ float buf[64 * 132];
  __shared__ int js[64];
  __shared__ float part[4][64];
  __shared__ float corrs[64];
  int blk = blockIdx.x;              // 768 = 2 * 384
  int b = blk / 384;
  int q0 = (blk - b * 384) * 64;
  int tid = threadIdx.x;
  int lane = tid & 63, wv = tid >> 6;
  int l15 = lane & 15, l4 = lane >> 4;

  if (tid < 64) js[tid] = nn_idx[b * HW + q0 + tid];
  __syncthreads();

  { // ---- corr phase ----
    int cg = tid >> 6, cpx = tid & 63;
    int q = q0 + cpx;
    int j = js[cpx];
    const float* sp = sampled + (size_t)(b * NPTS + j) * CH + cg * 32;
    const float* f2 = feat2d + (size_t)(b * CH + cg * 32) * HW + q;
    float acc = 0.f;
    #pragma unroll 8
    for (int i = 0; i < 32; ++i) acc += sp[i] * f2[(size_t)i * HW];
    part[cg][cpx] = acc;
    __syncthreads();
    if (cg == 0) {
      float s = (part[0][cpx] + part[1][cpx]) + (part[2][cpx] + part[3][cpx]);
      corrs[cpx] = s * 0.0078125f;
    }
    __syncthreads();
  }

  for (int i = tid; i < 64 * 33; i += 256) {
    int row = i / 33, c = i - row * 33;
    if (c < 32) {
      *(f32x4*)&buf[row * 132 + c * 4] =
          *(const f32x4*)&f3t[((size_t)(b * NPTS + js[row])) * CH + c * 4];
    } else {
      int q = q0 + row;
      int j = js[row];
      float u = uv[b * 2 * NPTS + j], v = uv[b * 2 * NPTS + NPTS + j];
      float xq = (float)(q % WID), yq = (float)(q / WID);
      f32x4 t = {u - xq, v - yq, corrs[row], 0.f};
      *(f32x4*)&buf[row * 132 + 128] = t;
    }
  }
  __syncthreads();

  float* og = out + (size_t)b * CH * HW + q0;
  conv_layer<true,  false>(buf, whl + 0 * 16384, whl + 1 * 16384, b1, w1full, og, wv, l15, l4);
  conv_layer<false, false>(buf, whl + 2 * 16384, whl + 3 * 16384, b2, nullptr, og, wv, l15, l4);
  conv_layer<false, true >(buf, whl + 4 * 16384, whl + 5 * 16384, b3, nullptr, og, wv, l15, l4);
}

extern "C" void kernel_launch(void* const* d_in, const int* in_sizes, int n_in,
                              void* d_out, int out_size, void* d_ws, size_t ws_size,
                              hipStream_t stream) {
  const float* uv     = (const float*)d_in[0];
  const float* feat2d = (const float*)d_in[1];
  const float* feat3d = (const float*)d_in[2];
  const float* w1 = (const float*)d_in[3];
  const float* b1 = (const float*)d_in[4];
  const float* w2 = (const float*)d_in[5];
  const float* b2 = (const float*)d_in[6];
  const float* w3 = (const float*)d_in[7];
  const float* b3 = (const float*)d_in[8];
  float* out = (float*)d_out;
  char* ws = (char*)d_ws;
  int*    nn_idx  = (int*)(ws + OFF_NNIDX);
  float*  sampled = (float*)(ws + OFF_SAMPLED);
  float*  f3t     = (float*)(ws + OFF_F3T);
  f16*    whl     = (f16*)(ws + OFF_WHL);
  float4* pts     = (float4*)(ws + OFF_PTS);
  int*    offs    = (int*)(ws + OFF_OFFS);

  k_bin <<<dim3(2),   dim3(512), 0, stream>>>(uv, pts, offs);
  k_main<<<dim3(960), dim3(512), 0, stream>>>(pts, offs, feat2d, feat3d,
                                              w1, w2, w3, nn_idx, sampled,
                                              f3t, whl);
  k_conv<<<dim3(768), dim3(256), 0, stream>>>(f3t, nn_idx, uv, feat2d, sampled,
                                              whl, w1, b1, b2, b3, out);
}

// Round 29
// 67.013 us; speedup vs baseline: 1.3915x; 1.1995x over previous
//
#include <hip/hip_runtime.h>

typedef _Float16 f16;
typedef f16  f16x8 __attribute__((ext_vector_type(8)));
typedef float f32x4 __attribute__((ext_vector_type(4)));

#define NPTS 4096
#define HW   24576
#define WID  192
#define CH   128
#define NCX  24
#define NCY  16
#define NCELL 384
#define EPS  0.15f

// ---- workspace layout (bytes) ----  (total 8978432, proven-safe size)
#define OFF_NNIDX   (0u)           // int[49152]
#define OFF_CORR    (196608u)      // region reused for pts/offs
#define OFF_SAMPLED (393216u)      // float[2][4096][128] = 4 MB
#define OFF_F3T     (4587520u)     // f16[8192*128] = 2 MB (was f32)
#define OFF_WHL     (8781824u)     // f16[3][2][128][128]
#define OFF_PTS     (OFF_CORR)             // float4[2][4096] = 131072 B
#define OFF_OFFS    (OFF_CORR + 131072u)   // int[2][385]     = 3080 B

__device__ __forceinline__ int cell_of(float u, float v) {
  int cx = (int)(u * 0.125f); cx = min(max(cx, 0), NCX - 1);
  int cy = (int)(v * 0.125f); cy = min(max(cy, 0), NCY - 1);
  return cy * NCX + cx;
}

// Binning only (2 blocks): count -> Hillis-Steele scan -> scatter
// float4{u, v, ssu_pinned, idx}.  ssu = RN(RN(u*u)+RN(v*v)) pinned.
__global__ __launch_bounds__(512) void k_bin(const float* __restrict__ uv,
                                             float4* __restrict__ pts,
                                             int* __restrict__ offs) {
#pragma clang fp contract(off)
  __shared__ int cnt[NCELL];
  __shared__ int base[NCELL + 1];
  __shared__ int sc[512];
  int b = blockIdx.x;
  int tid = threadIdx.x;
  const float* up = uv + b * 2 * NPTS;
  for (int i = tid; i < NCELL; i += 512) cnt[i] = 0;
  __syncthreads();
  for (int p = tid; p < NPTS; p += 512)
    atomicAdd(&cnt[cell_of(up[p], up[NPTS + p])], 1);
  __syncthreads();
  sc[tid] = (tid < NCELL) ? cnt[tid] : 0;
  __syncthreads();
  #pragma unroll
  for (int off = 1; off < 512; off <<= 1) {
    int val = (tid >= off) ? sc[tid - off] : 0;
    __syncthreads();
    sc[tid] += val;
    __syncthreads();
  }
  if (tid < NCELL) base[tid + 1] = sc[tid];
  if (tid == 0) base[0] = 0;
  __syncthreads();
  for (int i = tid; i <= NCELL; i += 512) offs[b * (NCELL + 1) + i] = base[i];
  for (int i = tid; i < NCELL; i += 512) cnt[i] = base[i];
  __syncthreads();
  for (int p = tid; p < NPTS; p += 512) {
    float u = up[p], v = up[NPTS + p];
    int pos = atomicAdd(&cnt[cell_of(u, v)], 1);
    float uu = u * u;   asm volatile("" : "+v"(uu));
    float vv = v * v;   asm volatile("" : "+v"(vv));
    float ss = uu + vv; asm volatile("" : "+v"(ss));
    float4 t; t.x = u; t.y = v; t.z = ss; t.w = __int_as_float(p);
    pts[b * NPTS + pos] = t;
  }
}

// Candidate evaluation: bit-exact pinned reference d2 + (d2,idx) lex-min.
__device__ __forceinline__ void cand_eval(float xq, float yq, float ssg,
                                          float4 pt, float& bestr, int& bir) {
  float xu = xq * pt.x;                       asm volatile("" : "+v"(xu));
  float qp = __builtin_fmaf(yq, pt.y, xu);    asm volatile("" : "+v"(qp));
  float tq = 2.0f * qp;                       asm volatile("" : "+v"(tq));
  float t1 = ssg - tq;                        asm volatile("" : "+v"(t1));
  float d2 = t1 + pt.z;                       asm volatile("" : "+v"(d2));
  int pi = __float_as_int(pt.w);
  if (d2 < bestr || (d2 == bestr && pi < bir)) { bestr = d2; bir = pi; }
}

// Fused main: [0..95] NN query; [96..351] binned sampling; [352..863]
// feat3d transpose (f32->f16); [864..959] weight hi/lo split.
__global__ __launch_bounds__(512, 1) void k_main(const float4* __restrict__ pts,
                                                 const int* __restrict__ offs,
                                                 const float* __restrict__ feat2d,
                                                 const float* __restrict__ feat3d,
                                                 const float* __restrict__ w1,
                                                 const float* __restrict__ w2,
                                                 const float* __restrict__ w3,
                                                 int* __restrict__ nn_idx,
                                                 float* __restrict__ sampled,
                                                 f16* __restrict__ f3t,
                                                 f16* __restrict__ whl) {
#pragma clang fp contract(off)
  __shared__ __align__(16) char smem[8448];
  int blk = blockIdx.x;
  int tid = threadIdx.x;
  if (blk >= 864) {             // ---- weight split: 96*512 = 49152
    int i = (blk - 864) * 512 + tid;
    int layer = i >> 14;
    int r = i & 16383;
    int o = r >> 7, k = r & 127;
    float v;
    if (layer == 0)      v = w1[o * 131 + 3 + k];
    else if (layer == 1) v = w2[o * 128 + k];
    else                 v = w3[o * 128 + k];
    f16 h = (f16)v;
    f16 l = (f16)(v - (float)h);
    whl[(layer * 2 + 0) * 16384 + r] = h;
    whl[(layer * 2 + 1) * 16384 + r] = l;
    return;
  }
  if (blk >= 352) {             // ---- transpose tile 32c x 64p -> f16
    float (*tile)[65] = (float (*)[65])smem;
    int t = blk - 352;          // 0..511
    int b = t >> 8;
    int r = t & 255;
    int cg = r >> 6, pg = r & 63;
    int c0 = cg * 32, p0 = pg * 64;
    {
      int p = tid & 63;
      int c = tid >> 6;         // 0..7, step 8
      #pragma unroll
      for (int cc = 0; cc < 32; cc += 8)
        tile[c + cc][p] = feat3d[(size_t)(b * CH + c0 + c + cc) * NPTS + p0 + p];
    }
    __syncthreads();
    {
      int c = tid & 31;
      int p = tid >> 5;         // 0..15, step 16
      #pragma unroll
      for (int pp = 0; pp < 64; pp += 16)
        f3t[(size_t)(b * NPTS + p0 + p + pp) * CH + c0 + c] = (f16)tile[c][p + pp];
    }
    return;
  }
  if (blk >= 96) {              // ---- binned-order sampling (256 blocks)
    float4* lpts = (float4*)smem;           // [32]
    int t = blk - 96;           // 0..255
    int b = t >> 7;
    int r0 = (t & 127) * 32;
    int c = tid & 127;
    int rsub = tid >> 7;        // 0..3
    const float* fp = feat2d + (size_t)(b * CH + c) * HW;
    if (tid < 32) lpts[tid] = pts[b * NPTS + r0 + tid];
    __syncthreads();
    float g00[8], g01[8], g10[8], g11[8], wxa[8], wya[8];
    int pidx[8];
    #pragma unroll
    for (int k = 0; k < 8; ++k) {
      float4 pt = lpts[rsub + 4 * k];
      float u = pt.x, v = pt.y;
      pidx[k] = __float_as_int(pt.w);
      float x0f = floorf(u), y0f = floorf(v);
      wxa[k] = u - x0f; wya[k] = v - y0f;
      int x0 = (int)x0f; x0 = min(max(x0, 0), WID - 1);
      int x1 = min(x0 + 1, WID - 1);
      int y0 = (int)y0f; y0 = min(max(y0, 0), 127);
      int y1 = min(y0 + 1, 127);
      g00[k] = fp[y0 * WID + x0]; g01[k] = fp[y0 * WID + x1];
      g10[k] = fp[y1 * WID + x0]; g11[k] = fp[y1 * WID + x1];
    }
    #pragma unroll
    for (int k = 0; k < 8; ++k) {
      float wx = wxa[k], wy = wya[k];
      float s = g00[k] * (1.f - wx) * (1.f - wy) + g01[k] * wx * (1.f - wy)
              + g10[k] * (1.f - wx) * wy + g11[k] * wx * wy;
      sampled[(size_t)(b * NPTS + pidx[k]) * CH + c] = s;
    }
    return;
  }
  // ---- NN query (96 blocks, 8 tiles each)
  int tile = blk * 8 + (tid >> 6);   // 768 tiles
  int lane = tid & 63;
  int b = tile / NCELL;
  int t = tile - b * NCELL;
  int ty = t / NCX, tx = t - ty * NCX;
  int px = tx * 8 + (lane & 7);
  int py = ty * 8 + (lane >> 3);
  float xq = (float)px, yq = (float)py;
  float ssg = xq * xq + yq * yq;
  const float4* P = pts + b * NPTS;
  const int* O = offs + b * (NCELL + 1);

  float m = 3.4e38f;
  float bestr = 3.4e38f; int bir = 0x7fffffff;

  for (int R = 0; R < 24; ++R) {
    if (R > 0) {
      float mm = m;
      #pragma unroll
      for (int o = 32; o; o >>= 1) mm = fmaxf(mm, __shfl_xor(mm, o));
      float bound = 64.f * (float)((R - 1) * (R - 1));
      if (bound > mm + EPS) break;
    }
    int x0 = max(0, tx - R), x1 = min(NCX - 1, tx + R);
    int y0 = max(0, ty - R), y1 = min(NCY - 1, ty + R);
    for (int cy = y0; cy <= y1; ++cy) {
      for (int cx = x0; cx <= x1; ++cx) {
        int cd = max(abs(cx - tx), abs(cy - ty));
        if (cd != R) continue;
        int c = cy * NCX + cx;
        int s = O[c], e = O[c + 1];
        int i = s;
        for (; i + 4 <= e; i += 4) {
          float4 p0 = P[i], p1 = P[i + 1], p2 = P[i + 2], p3 = P[i + 3];
          float dx0 = xq - p0.x, dy0 = yq - p0.y;
          float dx1 = xq - p1.x, dy1 = yq - p1.y;
          float dx2 = xq - p2.x, dy2 = yq - p2.y;
          float dx3 = xq - p3.x, dy3 = yq - p3.y;
          float a0 = fmaf(dy0, dy0, dx0 * dx0);
          float a1 = fmaf(dy1, dy1, dx1 * dx1);
          float a2 = fmaf(dy2, dy2, dx2 * dx2);
          float a3 = fmaf(dy3, dy3, dx3 * dx3);
          m = fminf(fminf(m, fminf(a0, a1)), fminf(a2, a3));
          if ((a0 <= m + EPS) | (a1 <= m + EPS) |
              (a2 <= m + EPS) | (a3 <= m + EPS)) {
            if (a0 <= m + EPS) cand_eval(xq, yq, ssg, p0, bestr, bir);
            if (a1 <= m + EPS) cand_eval(xq, yq, ssg, p1, bestr, bir);
            if (a2 <= m + EPS) cand_eval(xq, yq, ssg, p2, bestr, bir);
            if (a3 <= m + EPS) cand_eval(xq, yq, ssg, p3, bestr, bir);
          }
        }
        for (; i < e; ++i) {
          float4 pt = P[i];
          float dx = xq - pt.x, dy = yq - pt.y;
          float d2a = fmaf(dy, dy, dx * dx);
          m = fminf(m, d2a);
          if (d2a <= m + EPS) cand_eval(xq, yq, ssg, pt, bestr, bir);
        }
      }
    }
  }
  nn_idx[b * HW + py * WID + px] = bir;
}

// One conv layer, plain f16 MFMA (R15-grade precision), f32 accum.
// buf: f16 [64 px][136]; sideband sb[64][3] f32 applied in epilogue (layer 1).
template<bool LAYER1, bool LAST>
__device__ __forceinline__ void conv_layer(f16* buf, const float* sb,
                                           const f16* wh, const float* bias,
                                           const float* w1full, float* og,
                                           int wv, int l15, int l4) {
  f32x4 acc[2][4];
  #pragma unroll
  for (int r = 0; r < 2; ++r)
    #pragma unroll
    for (int c = 0; c < 4; ++c) acc[r][c] = (f32x4){0.f, 0.f, 0.f, 0.f};

  for (int k0 = 0; k0 < 128; k0 += 32) {
    f16x8 a0 = *(const f16x8*)&wh[(wv * 32 + l15) * 128 + k0 + l4 * 8];
    f16x8 a1 = *(const f16x8*)&wh[(wv * 32 + 16 + l15) * 128 + k0 + l4 * 8];
    #pragma unroll
    for (int c = 0; c < 4; ++c) {
      f16x8 bb = *(const f16x8*)&buf[(c * 16 + l15) * 136 + k0 + l4 * 8];
      acc[0][c] = __builtin_amdgcn_mfma_f32_16x16x32_f16(a0, bb, acc[0][c], 0, 0, 0);
      acc[1][c] = __builtin_amdgcn_mfma_f32_16x16x32_f16(a1, bb, acc[1][c], 0, 0, 0);
    }
  }
  __syncthreads();   // all reads of buf done before in-place overwrite
  #pragma unroll
  for (int r = 0; r < 2; ++r) {
    int ob = wv * 32 + r * 16 + l4 * 4;
    f32x4 bb = *(const f32x4*)&bias[ob];
    float w1c[4][3];
    if (LAYER1) {
      #pragma unroll
      for (int e = 0; e < 4; ++e) {
        w1c[e][0] = w1full[(ob + e) * 131 + 0];
        w1c[e][1] = w1full[(ob + e) * 131 + 1];
        w1c[e][2] = w1full[(ob + e) * 131 + 2];
      }
    }
    #pragma unroll
    for (int c = 0; c < 4; ++c) {
      int p = c * 16 + l15;
      float s0 = 0.f, s1 = 0.f, s2 = 0.f;
      if (LAYER1) { s0 = sb[p * 4 + 0]; s1 = sb[p * 4 + 1]; s2 = sb[p * 4 + 2]; }
      union { f16 h[4]; uint2 u2; } pk;
      #pragma unroll
      for (int e = 0; e < 4; ++e) {
        float y = acc[r][c][e] + bb[e];
        if (LAYER1) y += w1c[e][0] * s0 + w1c[e][1] * s1 + w1c[e][2] * s2;
        y = (y >= 0.f) ? y : 0.1f * y;
        if (LAST) og[(size_t)(ob + e) * HW + p] = y;
        else pk.h[e] = (f16)y;
      }
      if (!LAST) *(uint2*)&buf[p * 136 + ob] = pk.u2;
    }
  }
  __syncthreads();
}

// Fused corr + 3-layer plain-f16 conv. Block = 256 thr, tile = 128oc x 64px.
__global__ __launch_bounds__(256) void k_conv(const f16* __restrict__ f3t,
                                              const int* __restrict__ nn_idx,
                                              const float* __restrict__ uv,
                                              const float* __restrict__ feat2d,
                                              const float* __restrict__ sampled,
                                              const f16* __restrict__ whl,
                                              const float* __restrict__ w1full,
                                              const float* __restrict__ b1,
                                              const float* __restrict__ b2,
                                              const float* __restrict__ b3,
                                              float* __restrict__ out) {
  __shared__ f16 buf[64 * 136];
  __shared__ float sb[64 * 4];
  __shared__ int js[64];
  __shared__ float part[4][64];
  int blk = blockIdx.x;              // 768 = 2 * 384
  int b = blk / 384;
  int q0 = (blk - b * 384) * 64;
  int tid = threadIdx.x;
  int lane = tid & 63, wv = tid >> 6;
  int l15 = lane & 15, l4 = lane >> 4;

  if (tid < 64) js[tid] = nn_idx[b * HW + q0 + tid];
  __syncthreads();

  { // ---- corr phase (verified accumulation order) ----
    int cg = tid >> 6, cpx = tid & 63;
    int q = q0 + cpx;
    int j = js[cpx];
    const float* sp = sampled + (size_t)(b * NPTS + j) * CH + cg * 32;
    const float* f2 = feat2d + (size_t)(b * CH + cg * 32) * HW + q;
    float acc = 0.f;
    #pragma unroll 8
    for (int i = 0; i < 32; ++i) acc += sp[i] * f2[(size_t)i * HW];
    part[cg][cpx] = acc;
    __syncthreads();
    if (cg == 0) {
      float s = (part[0][cpx] + part[1][cpx]) + (part[2][cpx] + part[3][cpx]);
      float u = uv[b * 2 * NPTS + j], v = uv[b * 2 * NPTS + NPTS + j];
      float xq = (float)(q % WID), yq = (float)(q / WID);
      sb[cpx * 4 + 0] = u - xq;
      sb[cpx * 4 + 1] = v - yq;
      sb[cpx * 4 + 2] = s * 0.0078125f;
    }
    __syncthreads();
  }

  { // ---- stage f3t rows (f16, 256B each = 16 uint4) ----
    for (int i = tid; i < 64 * 16; i += 256) {
      int row = i >> 4, chk = i & 15;
      *(uint4*)&buf[row * 136 + chk * 8] =
          *(const uint4*)&f3t[((size_t)(b * NPTS + js[row])) * CH + chk * 8];
    }
    #pragma unroll
    for (int i = tid; i < 64; i += 256) {
      *(uint4*)&buf[i * 136 + 128] = (uint4){0, 0, 0, 0};
    }
  }
  __syncthreads();

  float* og = out + (size_t)b * CH * HW + q0;
  conv_layer<true,  false>(buf, sb, whl + 0 * 16384, b1, w1full, og, wv, l15, l4);
  conv_layer<false, false>(buf, sb, whl + 2 * 16384, b2, nullptr, og, wv, l15, l4);
  conv_layer<false, true >(buf, sb, whl + 4 * 16384, b3, nullptr, og, wv, l15, l4);
}

extern "C" void kernel_launch(void* const* d_in, const int* in_sizes, int n_in,
                              void* d_out, int out_size, void* d_ws, size_t ws_size,
                              hipStream_t stream) {
  const float* uv     = (const float*)d_in[0];
  const float* feat2d = (const float*)d_in[1];
  const float* feat3d = (const float*)d_in[2];
  const float* w1 = (const float*)d_in[3];
  const float* b1 = (const float*)d_in[4];
  const float* w2 = (const float*)d_in[5];
  const float* b2 = (const float*)d_in[6];
  const float* w3 = (const float*)d_in[7];
  const float* b3 = (const float*)d_in[8];
  float* out = (float*)d_out;
  char* ws = (char*)d_ws;
  int*    nn_idx  = (int*)(ws + OFF_NNIDX);
  float*  sampled = (float*)(ws + OFF_SAMPLED);
  f16*    f3t     = (f16*)(ws + OFF_F3T);
  f16*    whl     = (f16*)(ws + OFF_WHL);
  float4* pts     = (float4*)(ws + OFF_PTS);
  int*    offs    = (int*)(ws + OFF_OFFS);

  k_bin <<<dim3(2),   dim3(512), 0, stream>>>(uv, pts, offs);
  k_main<<<dim3(960), dim3(512), 0, stream>>>(pts, offs, feat2d, feat3d,
                                              w1, w2, w3, nn_idx, sampled,
                                              f3t, whl);
  k_conv<<<dim3(768), dim3(256), 0, stream>>>(f3t, nn_idx, uv, feat2d, sampled,
                                              whl, w1, b1, b2, b3, out);
}

// Round 30
// 61.278 us; speedup vs baseline: 1.5218x; 1.0936x over previous
//
#include <hip/hip_runtime.h>

typedef _Float16 f16;
typedef f16  f16x8 __attribute__((ext_vector_type(8)));
typedef float f32x4 __attribute__((ext_vector_type(4)));

#define NPTS 4096
#define HW   24576
#define WID  192
#define CH   128
#define NCX  24
#define NCY  16
#define NCELL 384
#define EPS  0.15f

// ---- workspace layout (bytes) ----  (total 8978432, proven-safe size)
#define OFF_NNIDX   (0u)           // int[49152]
#define OFF_CORR    (196608u)      // region reused for pts/offs
#define OFF_SAMPLED (393216u)      // float[2][4096][128] = 4 MB
#define OFF_F3T     (4587520u)     // f16[8192*128] = 2 MB
#define OFF_WHL     (8781824u)     // f16[3][2][128][128]
#define OFF_PTS     (OFF_CORR)             // float4[2][4096] = 131072 B
#define OFF_OFFS    (OFF_CORR + 131072u)   // int[2][385]     = 3080 B

__device__ __forceinline__ int cell_of(float u, float v) {
  int cx = (int)(u * 0.125f); cx = min(max(cx, 0), NCX - 1);
  int cy = (int)(v * 0.125f); cy = min(max(cy, 0), NCY - 1);
  return cy * NCX + cx;
}

// Binning (2 blocks x 1024): count -> Hillis-Steele scan -> scatter
// float4{u, v, ssu_pinned, idx}.  ssu = RN(RN(u*u)+RN(v*v)) pinned.
__global__ __launch_bounds__(1024) void k_bin(const float* __restrict__ uv,
                                              float4* __restrict__ pts,
                                              int* __restrict__ offs) {
#pragma clang fp contract(off)
  __shared__ int cnt[NCELL];
  __shared__ int base[NCELL + 1];
  __shared__ int sc[1024];
  int b = blockIdx.x;
  int tid = threadIdx.x;
  const float* up = uv + b * 2 * NPTS;
  for (int i = tid; i < NCELL; i += 1024) cnt[i] = 0;
  __syncthreads();
  for (int p = tid; p < NPTS; p += 1024)
    atomicAdd(&cnt[cell_of(up[p], up[NPTS + p])], 1);
  __syncthreads();
  sc[tid] = (tid < NCELL) ? cnt[tid] : 0;
  __syncthreads();
  #pragma unroll
  for (int off = 1; off < 512; off <<= 1) {
    int val = (tid >= off) ? sc[tid - off] : 0;
    __syncthreads();
    sc[tid] += val;
    __syncthreads();
  }
  if (tid < NCELL) base[tid + 1] = sc[tid];
  if (tid == 0) base[0] = 0;
  __syncthreads();
  for (int i = tid; i <= NCELL; i += 1024) offs[b * (NCELL + 1) + i] = base[i];
  for (int i = tid; i < NCELL; i += 1024) cnt[i] = base[i];
  __syncthreads();
  for (int p = tid; p < NPTS; p += 1024) {
    float u = up[p], v = up[NPTS + p];
    int pos = atomicAdd(&cnt[cell_of(u, v)], 1);
    float uu = u * u;   asm volatile("" : "+v"(uu));
    float vv = v * v;   asm volatile("" : "+v"(vv));
    float ss = uu + vv; asm volatile("" : "+v"(ss));
    float4 t; t.x = u; t.y = v; t.z = ss; t.w = __int_as_float(p);
    pts[b * NPTS + pos] = t;
  }
}

// Candidate evaluation: bit-exact pinned reference d2 + (d2,idx) lex-min.
__device__ __forceinline__ void cand_eval(float xq, float yq, float ssg,
                                          float4 pt, float& bestr, int& bir) {
  float xu = xq * pt.x;                       asm volatile("" : "+v"(xu));
  float qp = __builtin_fmaf(yq, pt.y, xu);    asm volatile("" : "+v"(qp));
  float tq = 2.0f * qp;                       asm volatile("" : "+v"(tq));
  float t1 = ssg - tq;                        asm volatile("" : "+v"(t1));
  float d2 = t1 + pt.z;                       asm volatile("" : "+v"(d2));
  int pi = __float_as_int(pt.w);
  if (d2 < bestr || (d2 == bestr && pi < bir)) { bestr = d2; bir = pi; }
}

// Fused main (1024-thr blocks): [0..47] NN query (16 tiles/block);
// [48..303] binned sampling (8 ranks concurrent x unroll-4);
// [304..815] feat3d transpose f32->f16; [816..863] weight hi/lo split.
__global__ __launch_bounds__(1024, 1) void k_main(const float4* __restrict__ pts,
                                                  const int* __restrict__ offs,
                                                  const float* __restrict__ feat2d,
                                                  const float* __restrict__ feat3d,
                                                  const float* __restrict__ w1,
                                                  const float* __restrict__ w2,
                                                  const float* __restrict__ w3,
                                                  int* __restrict__ nn_idx,
                                                  float* __restrict__ sampled,
                                                  f16* __restrict__ f3t,
                                                  f16* __restrict__ whl) {
#pragma clang fp contract(off)
  __shared__ __align__(16) char smem[8448];
  int blk = blockIdx.x;
  int tid = threadIdx.x;
  if (blk >= 816) {             // ---- weight split: 48*1024 = 49152
    int i = (blk - 816) * 1024 + tid;
    int layer = i >> 14;
    int r = i & 16383;
    int o = r >> 7, k = r & 127;
    float v;
    if (layer == 0)      v = w1[o * 131 + 3 + k];
    else if (layer == 1) v = w2[o * 128 + k];
    else                 v = w3[o * 128 + k];
    f16 h = (f16)v;
    f16 l = (f16)(v - (float)h);
    whl[(layer * 2 + 0) * 16384 + r] = h;
    whl[(layer * 2 + 1) * 16384 + r] = l;
    return;
  }
  if (blk >= 304) {             // ---- transpose tile 32c x 64p -> f16
    float (*tile)[65] = (float (*)[65])smem;
    int t = blk - 304;          // 0..511
    int b = t >> 8;
    int r = t & 255;
    int cg = r >> 6, pg = r & 63;
    int c0 = cg * 32, p0 = pg * 64;
    {
      int p = tid & 63;
      int c = tid >> 6;         // 0..15, step 16
      #pragma unroll
      for (int cc = 0; cc < 32; cc += 16)
        tile[c + cc][p] = feat3d[(size_t)(b * CH + c0 + c + cc) * NPTS + p0 + p];
    }
    __syncthreads();
    {
      int c = tid & 31;
      int p = tid >> 5;         // 0..31, step 32
      #pragma unroll
      for (int pp = 0; pp < 64; pp += 32)
        f3t[(size_t)(b * NPTS + p0 + p + pp) * CH + c0 + c] = (f16)tile[c][p + pp];
    }
    return;
  }
  if (blk >= 48) {              // ---- binned-order sampling (256 blocks)
    float4* lpts = (float4*)smem;           // [32]
    int t = blk - 48;           // 0..255
    int b = t >> 7;
    int r0 = (t & 127) * 32;
    int c = tid & 127;
    int rsub = tid >> 7;        // 0..7
    const float* fp = feat2d + (size_t)(b * CH + c) * HW;
    if (tid < 32) lpts[tid] = pts[b * NPTS + r0 + tid];
    __syncthreads();
    float g00[4], g01[4], g10[4], g11[4], wxa[4], wya[4];
    int pidx[4];
    #pragma unroll
    for (int k = 0; k < 4; ++k) {
      float4 pt = lpts[rsub + 8 * k];
      float u = pt.x, v = pt.y;
      pidx[k] = __float_as_int(pt.w);
      float x0f = floorf(u), y0f = floorf(v);
      wxa[k] = u - x0f; wya[k] = v - y0f;
      int x0 = (int)x0f; x0 = min(max(x0, 0), WID - 1);
      int x1 = min(x0 + 1, WID - 1);
      int y0 = (int)y0f; y0 = min(max(y0, 0), 127);
      int y1 = min(y0 + 1, 127);
      g00[k] = fp[y0 * WID + x0]; g01[k] = fp[y0 * WID + x1];
      g10[k] = fp[y1 * WID + x0]; g11[k] = fp[y1 * WID + x1];
    }
    #pragma unroll
    for (int k = 0; k < 4; ++k) {
      float wx = wxa[k], wy = wya[k];
      float s = g00[k] * (1.f - wx) * (1.f - wy) + g01[k] * wx * (1.f - wy)
              + g10[k] * (1.f - wx) * wy + g11[k] * wx * wy;
      sampled[(size_t)(b * NPTS + pidx[k]) * CH + c] = s;
    }
    return;
  }
  // ---- NN query (48 blocks, 16 tiles each)
  int tile = blk * 16 + (tid >> 6);  // 768 tiles
  int lane = tid & 63;
  int b = tile / NCELL;
  int t = tile - b * NCELL;
  int ty = t / NCX, tx = t - ty * NCX;
  int px = tx * 8 + (lane & 7);
  int py = ty * 8 + (lane >> 3);
  float xq = (float)px, yq = (float)py;
  float ssg = xq * xq + yq * yq;
  const float4* P = pts + b * NPTS;
  const int* O = offs + b * (NCELL + 1);

  float m = 3.4e38f;
  float bestr = 3.4e38f; int bir = 0x7fffffff;

  for (int R = 0; R < 24; ++R) {
    if (R > 0) {
      float mm = m;
      #pragma unroll
      for (int o = 32; o; o >>= 1) mm = fmaxf(mm, __shfl_xor(mm, o));
      float bound = 64.f * (float)((R - 1) * (R - 1));
      if (bound > mm + EPS) break;
    }
    int x0 = max(0, tx - R), x1 = min(NCX - 1, tx + R);
    int y0 = max(0, ty - R), y1 = min(NCY - 1, ty + R);
    for (int cy = y0; cy <= y1; ++cy) {
      for (int cx = x0; cx <= x1; ++cx) {
        int cd = max(abs(cx - tx), abs(cy - ty));
        if (cd != R) continue;
        int c = cy * NCX + cx;
        int s = O[c], e = O[c + 1];
        int i = s;
        for (; i + 4 <= e; i += 4) {
          float4 p0 = P[i], p1 = P[i + 1], p2 = P[i + 2], p3 = P[i + 3];
          float dx0 = xq - p0.x, dy0 = yq - p0.y;
          float dx1 = xq - p1.x, dy1 = yq - p1.y;
          float dx2 = xq - p2.x, dy2 = yq - p2.y;
          float dx3 = xq - p3.x, dy3 = yq - p3.y;
          float a0 = fmaf(dy0, dy0, dx0 * dx0);
          float a1 = fmaf(dy1, dy1, dx1 * dx1);
          float a2 = fmaf(dy2, dy2, dx2 * dx2);
          float a3 = fmaf(dy3, dy3, dx3 * dx3);
          m = fminf(fminf(m, fminf(a0, a1)), fminf(a2, a3));
          if ((a0 <= m + EPS) | (a1 <= m + EPS) |
              (a2 <= m + EPS) | (a3 <= m + EPS)) {
            if (a0 <= m + EPS) cand_eval(xq, yq, ssg, p0, bestr, bir);
            if (a1 <= m + EPS) cand_eval(xq, yq, ssg, p1, bestr, bir);
            if (a2 <= m + EPS) cand_eval(xq, yq, ssg, p2, bestr, bir);
            if (a3 <= m + EPS) cand_eval(xq, yq, ssg, p3, bestr, bir);
          }
        }
        for (; i < e; ++i) {
          float4 pt = P[i];
          float dx = xq - pt.x, dy = yq - pt.y;
          float d2a = fmaf(dy, dy, dx * dx);
          m = fminf(m, d2a);
          if (d2a <= m + EPS) cand_eval(xq, yq, ssg, pt, bestr, bir);
        }
      }
    }
  }
  nn_idx[b * HW + py * WID + px] = bir;
}

// One conv layer, plain f16 MFMA, f32 accum.
// buf: f16 [64 px][136]; sideband sb[64][3] f32 applied in epilogue (layer 1).
template<bool LAYER1, bool LAST>
__device__ __forceinline__ void conv_layer(f16* buf, const float* sb,
                                           const f16* wh, const float* bias,
                                           const float* w1full, float* og,
                                           int wv, int l15, int l4) {
  f32x4 acc[2][4];
  #pragma unroll
  for (int r = 0; r < 2; ++r)
    #pragma unroll
    for (int c = 0; c < 4; ++c) acc[r][c] = (f32x4){0.f, 0.f, 0.f, 0.f};

  for (int k0 = 0; k0 < 128; k0 += 32) {
    f16x8 a0 = *(const f16x8*)&wh[(wv * 32 + l15) * 128 + k0 + l4 * 8];
    f16x8 a1 = *(const f16x8*)&wh[(wv * 32 + 16 + l15) * 128 + k0 + l4 * 8];
    #pragma unroll
    for (int c = 0; c < 4; ++c) {
      f16x8 bb = *(const f16x8*)&buf[(c * 16 + l15) * 136 + k0 + l4 * 8];
      acc[0][c] = __builtin_amdgcn_mfma_f32_16x16x32_f16(a0, bb, acc[0][c], 0, 0, 0);
      acc[1][c] = __builtin_amdgcn_mfma_f32_16x16x32_f16(a1, bb, acc[1][c], 0, 0, 0);
    }
  }
  __syncthreads();   // all reads of buf done before in-place overwrite
  #pragma unroll
  for (int r = 0; r < 2; ++r) {
    int ob = wv * 32 + r * 16 + l4 * 4;
    f32x4 bb = *(const f32x4*)&bias[ob];
    float w1c[4][3];
    if (LAYER1) {
      #pragma unroll
      for (int e = 0; e < 4; ++e) {
        w1c[e][0] = w1full[(ob + e) * 131 + 0];
        w1c[e][1] = w1full[(ob + e) * 131 + 1];
        w1c[e][2] = w1full[(ob + e) * 131 + 2];
      }
    }
    #pragma unroll
    for (int c = 0; c < 4; ++c) {
      int p = c * 16 + l15;
      float s0 = 0.f, s1 = 0.f, s2 = 0.f;
      if (LAYER1) { s0 = sb[p * 4 + 0]; s1 = sb[p * 4 + 1]; s2 = sb[p * 4 + 2]; }
      union { f16 h[4]; uint2 u2; } pk;
      #pragma unroll
      for (int e = 0; e < 4; ++e) {
        float y = acc[r][c][e] + bb[e];
        if (LAYER1) y += w1c[e][0] * s0 + w1c[e][1] * s1 + w1c[e][2] * s2;
        y = (y >= 0.f) ? y : 0.1f * y;
        if (LAST) og[(size_t)(ob + e) * HW + p] = y;
        else pk.h[e] = (f16)y;
      }
      if (!LAST) *(uint2*)&buf[p * 136 + ob] = pk.u2;
    }
  }
  __syncthreads();
}

// Fused corr + 3-layer plain-f16 conv. Block = 256 thr, tile = 128oc x 64px.
__global__ __launch_bounds__(256) void k_conv(const f16* __restrict__ f3t,
                                              const int* __restrict__ nn_idx,
                                              const float* __restrict__ uv,
                                              const float* __restrict__ feat2d,
                                              const float* __restrict__ sampled,
                                              const f16* __restrict__ whl,
                                              const float* __restrict__ w1full,
                                              const float* __restrict__ b1,
                                              const float* __restrict__ b2,
                                              const float* __restrict__ b3,
                                              float* __restrict__ out) {
  __shared__ f16 buf[64 * 136];
  __shared__ float sb[64 * 4];
  __shared__ int js[64];
  __shared__ float part[4][64];
  int blk = blockIdx.x;              // 768 = 2 * 384
  int b = blk / 384;
  int q0 = (blk - b * 384) * 64;
  int tid = threadIdx.x;
  int lane = tid & 63, wv = tid >> 6;
  int l15 = lane & 15, l4 = lane >> 4;

  if (tid < 64) js[tid] = nn_idx[b * HW + q0 + tid];
  __syncthreads();

  { // ---- corr phase (verified accumulation order) ----
    int cg = tid >> 6, cpx = tid & 63;
    int q = q0 + cpx;
    int j = js[cpx];
    const float* sp = sampled + (size_t)(b * NPTS + j) * CH + cg * 32;
    const float* f2 = feat2d + (size_t)(b * CH + cg * 32) * HW + q;
    float acc = 0.f;
    #pragma unroll 8
    for (int i = 0; i < 32; ++i) acc += sp[i] * f2[(size_t)i * HW];
    part[cg][cpx] = acc;
    __syncthreads();
    if (cg == 0) {
      float s = (part[0][cpx] + part[1][cpx]) + (part[2][cpx] + part[3][cpx]);
      float u = uv[b * 2 * NPTS + j], v = uv[b * 2 * NPTS + NPTS + j];
      float xq = (float)(q % WID), yq = (float)(q / WID);
      sb[cpx * 4 + 0] = u - xq;
      sb[cpx * 4 + 1] = v - yq;
      sb[cpx * 4 + 2] = s * 0.0078125f;
    }
    __syncthreads();
  }

  { // ---- stage f3t rows (f16, 256B each = 16 uint4) ----
    for (int i = tid; i < 64 * 16; i += 256) {
      int row = i >> 4, chk = i & 15;
      *(uint4*)&buf[row * 136 + chk * 8] =
          *(const uint4*)&f3t[((size_t)(b * NPTS + js[row])) * CH + chk * 8];
    }
    #pragma unroll
    for (int i = tid; i < 64; i += 256) {
      *(uint4*)&buf[i * 136 + 128] = (uint4){0, 0, 0, 0};
    }
  }
  __syncthreads();

  float* og = out + (size_t)b * CH * HW + q0;
  conv_layer<true,  false>(buf, sb, whl + 0 * 16384, b1, w1full, og, wv, l15, l4);
  conv_layer<false, false>(buf, sb, whl + 2 * 16384, b2, nullptr, og, wv, l15, l4);
  conv_layer<false, true >(buf, sb, whl + 4 * 16384, b3, nullptr, og, wv, l15, l4);
}

extern "C" void kernel_launch(void* const* d_in, const int* in_sizes, int n_in,
                              void* d_out, int out_size, void* d_ws, size_t ws_size,
                              hipStream_t stream) {
  const float* uv     = (const float*)d_in[0];
  const float* feat2d = (const float*)d_in[1];
  const float* feat3d = (const float*)d_in[2];
  const float* w1 = (const float*)d_in[3];
  const float* b1 = (const float*)d_in[4];
  const float* w2 = (const float*)d_in[5];
  const float* b2 = (const float*)d_in[6];
  const float* w3 = (const float*)d_in[7];
  const float* b3 = (const float*)d_in[8];
  float* out = (float*)d_out;
  char* ws = (char*)d_ws;
  int*    nn_idx  = (int*)(ws + OFF_NNIDX);
  float*  sampled = (float*)(ws + OFF_SAMPLED);
  f16*    f3t     = (f16*)(ws + OFF_F3T);
  f16*    whl     = (f16*)(ws + OFF_WHL);
  float4* pts     = (float4*)(ws + OFF_PTS);
  int*    offs    = (int*)(ws + OFF_OFFS);

  k_bin <<<dim3(2),   dim3(1024), 0, stream>>>(uv, pts, offs);
  k_main<<<dim3(864), dim3(1024), 0, stream>>>(pts, offs, feat2d, feat3d,
                                               w1, w2, w3, nn_idx, sampled,
                                               f3t, whl);
  k_conv<<<dim3(768), dim3(256),  0, stream>>>(f3t, nn_idx, uv, feat2d, sampled,
                                               whl, w1, b1, b2, b3, out);
}